// Round 12
// baseline (420.729 us; speedup 1.0000x reference)
//
#include <hip/hip_runtime.h>
#include <hip/hip_bf16.h>
#include <stdint.h>

// Problem constants
#define B_ 2
#define T_ 1024
#define H_ 32
#define N_ 64
#define HN_ 2048
#define KVH_ 8
#define KVD_ 512
#define MTOK 2048        // B*T
#define SMN 7168         // concat small-gemm output width
#define KCAT 320
#define CH 64            // scan chunk length
#define NCH 16           // T/CH
#define NCHUNK 1024      // B*H*NCH

typedef __bf16 bf16x8 __attribute__((ext_vector_type(8)));
typedef float f32x4 __attribute__((ext_vector_type(4)));

typedef __attribute__((address_space(1))) uint32_t gu32;
typedef __attribute__((address_space(3))) uint32_t lu32;
__device__ __forceinline__ void gload16(const void* g, void* l) {
    __builtin_amdgcn_global_load_lds((gu32*)g, (lu32*)l, 16, 0, 0);
}

__device__ __forceinline__ float sigmf(float x) { return 1.f / (1.f + expf(-x)); }

// ---------------- merged prep kernel: f2b(RKV_w) | f2b(O_w) | transpose(wavgk1) | wcat ----------------
#define PREP_N1 (3072 * 2048)
#define PREP_N2 (2048 * 2048)
#define PREP_N3 (320 * 2048)
#define PREP_N4 (SMN * KCAT)
__global__ void prep_kernel(const float* __restrict__ RKV_w, const float* __restrict__ O_w,
                            const float* __restrict__ wavgk1,
                            const float* __restrict__ w2, const float* __restrict__ a2,
                            const float* __restrict__ v2, const float* __restrict__ g2,
                            const float* __restrict__ k2,
                            __hip_bfloat16* __restrict__ RKVb, __hip_bfloat16* __restrict__ OWb,
                            __hip_bfloat16* __restrict__ WT1b, __hip_bfloat16* __restrict__ Wcatb) {
    long i = (long)blockIdx.x * 256 + threadIdx.x;
    if (i < PREP_N1) { RKVb[i] = __float2bfloat16(RKV_w[i]); return; }
    i -= PREP_N1;
    if (i < PREP_N2) { OWb[i] = __float2bfloat16(O_w[i]); return; }
    i -= PREP_N2;
    if (i < PREP_N3) {
        int c = (int)(i / 2048), r = (int)(i % 2048);
        WT1b[i] = __float2bfloat16(wavgk1[(size_t)r * 320 + c]);
        return;
    }
    i -= PREP_N3;
    if (i >= PREP_N4) return;
    int j = (int)(i / KCAT), k = (int)(i % KCAT);
    float v = 0.f;
    if (j < 2048)      { if (k < 64)             v = w2[(size_t)k * 2048 + j]; }
    else if (j < 4096) { if (k >= 64 && k < 128)  v = a2[(size_t)(k - 64) * 2048 + (j - 2048)]; }
    else if (j < 4608) { if (k >= 128 && k < 160) v = v2[(size_t)(k - 128) * 512 + (j - 4096)]; }
    else if (j < 6656) { if (k >= 160 && k < 288) v = g2[(size_t)(k - 160) * 2048 + (j - 4608)]; }
    else               { if (k >= 288)            v = k2[(size_t)(k - 288) * 512 + (j - 6656)]; }
    Wcatb[i] = __float2bfloat16(v);
}

// ---------------- RMSNorm over HN per token -> bf16 ----------------
__global__ __launch_bounds__(256) void rmsnorm_kernel(const float* __restrict__ x,
                                                      const float* __restrict__ ln1,
                                                      __hip_bfloat16* __restrict__ out) {
    const int bt = blockIdx.x, tid = threadIdx.x;
    const float* row = x + (size_t)bt * HN_;
    float4 v0 = *(const float4*)(row + tid * 8);
    float4 v1 = *(const float4*)(row + tid * 8 + 4);
    float s = v0.x*v0.x + v0.y*v0.y + v0.z*v0.z + v0.w*v0.w
            + v1.x*v1.x + v1.y*v1.y + v1.z*v1.z + v1.w*v1.w;
    for (int m = 1; m < 64; m <<= 1) s += __shfl_xor(s, m);
    __shared__ float red[4];
    if ((tid & 63) == 0) red[tid >> 6] = s;
    __syncthreads();
    s = red[0] + red[1] + red[2] + red[3];
    float scale = rsqrtf(s * (1.f / HN_) + 1e-6f);
    float vals[8] = {v0.x, v0.y, v0.z, v0.w, v1.x, v1.y, v1.z, v1.w};
    #pragma unroll
    for (int j = 0; j < 8; ++j)
        out[(size_t)bt * HN_ + tid * 8 + j] = __float2bfloat16(vals[j] * scale * ln1[tid * 8 + j]);
}

// ---------------- split-K 64-tile GEMM for XW (N=320): partial f32 out ----------------
__global__ __launch_bounds__(256) void gemm_xw_sk(const __hip_bfloat16* __restrict__ A,
                                                  const __hip_bfloat16* __restrict__ B,
                                                  float* __restrict__ Cp, int M, int N, int K) {
    __shared__ __align__(16) __hip_bfloat16 As[64][40];
    __shared__ __align__(16) __hip_bfloat16 Bs[64][40];
    const int tid = threadIdx.x;
    const int wave = tid >> 6, lane = tid & 63;
    const int wr = (wave >> 1) * 32, wc = (wave & 1) * 32;
    const int brow = blockIdx.y << 6, bcol = blockIdx.x << 6;
    const int z = blockIdx.z;
    const int kbeg = z * (K >> 2), kend = kbeg + (K >> 2);
    const int lrow = tid >> 2, lcol = (tid & 3) << 3;
    const int fr = lane & 15, ko = (lane >> 4) << 3;
    f32x4 acc[2][2] = {};
    for (int k0 = kbeg; k0 < kend; k0 += 32) {
        uint4 av = *(const uint4*)(A + (size_t)(brow + lrow) * K + k0 + lcol);
        uint4 bv = *(const uint4*)(B + (size_t)(bcol + lrow) * K + k0 + lcol);
        *(uint4*)(&As[lrow][lcol]) = av;
        *(uint4*)(&Bs[lrow][lcol]) = bv;
        __syncthreads();
        bf16x8 af0 = *(const bf16x8*)(&As[wr + fr][ko]);
        bf16x8 af1 = *(const bf16x8*)(&As[wr + 16 + fr][ko]);
        bf16x8 bf0 = *(const bf16x8*)(&Bs[wc + fr][ko]);
        bf16x8 bf1 = *(const bf16x8*)(&Bs[wc + 16 + fr][ko]);
        acc[0][0] = __builtin_amdgcn_mfma_f32_16x16x32_bf16(af0, bf0, acc[0][0], 0, 0, 0);
        acc[0][1] = __builtin_amdgcn_mfma_f32_16x16x32_bf16(af0, bf1, acc[0][1], 0, 0, 0);
        acc[1][0] = __builtin_amdgcn_mfma_f32_16x16x32_bf16(af1, bf0, acc[1][0], 0, 0, 0);
        acc[1][1] = __builtin_amdgcn_mfma_f32_16x16x32_bf16(af1, bf1, acc[1][1], 0, 0, 0);
        __syncthreads();
    }
    const int cr = (lane >> 4) << 2, cc = lane & 15;
    float* Cz = Cp + (size_t)z * M * N;
    #pragma unroll
    for (int i = 0; i < 2; ++i)
        #pragma unroll
        for (int j = 0; j < 2; ++j)
            #pragma unroll
            for (int r = 0; r < 4; ++r) {
                int row = brow + wr + i * 16 + cr + r;
                int col = bcol + wc + j * 16 + cc;
                Cz[(size_t)row * N + col] = acc[i][j][r];
            }
}

// ---------------- reduce split-K partials + xw activation -> bf16 ----------------
__global__ void xw_reduce(const float* __restrict__ Cp, __hip_bfloat16* __restrict__ out) {
    long i = (long)blockIdx.x * 256 + threadIdx.x;
    if (i >= (long)MTOK * KCAT) return;
    const long MN = (long)MTOK * KCAT;
    float v = Cp[i] + Cp[i + MN] + Cp[i + 2 * MN] + Cp[i + 3 * MN];
    int c = (int)(i % KCAT);
    if (c < 64) v = tanhf(v);
    else if (c >= 160 && c < 288) v = sigmf(v);
    out[i] = __float2bfloat16(v);
}

// ---------------- 128-tile MFMA GEMM with global_load_lds staging (m97 pattern) ----------------
__global__ __launch_bounds__(256) void gemm_bt128(const __hip_bfloat16* __restrict__ A,
                                                  const __hip_bfloat16* __restrict__ B,
                                                  float* __restrict__ C, int M, int N, int K,
                                                  const float* __restrict__ bias,
                                                  const float* __restrict__ addend) {
    __shared__ __align__(16) __hip_bfloat16 As[128][32];
    __shared__ __align__(16) __hip_bfloat16 Bs[128][32];
    const int tid = threadIdx.x;
    const int wave = tid >> 6, lane = tid & 63;
    const int wr = (wave >> 1) * 64, wc = (wave & 1) * 64;
    const int brow = blockIdx.y << 7, bcol = blockIdx.x << 7;
    const int fr = lane & 15, ko = (lane >> 4) << 3;
    const int ar0 = wave * 32;            // wave's staging row block
    const int sr = lane >> 2;             // row within 16-row group
    const int sc = (lane & 3) << 3;       // k-elem offset (8 elems = 16 B)
    f32x4 acc[4][4] = {};
    const __hip_bfloat16* gA0 = A + (size_t)(brow + ar0 + sr) * K + sc;
    const __hip_bfloat16* gA1 = A + (size_t)(brow + ar0 + 16 + sr) * K + sc;
    const __hip_bfloat16* gB0 = B + (size_t)(bcol + ar0 + sr) * K + sc;
    const __hip_bfloat16* gB1 = B + (size_t)(bcol + ar0 + 16 + sr) * K + sc;
    for (int k0 = 0; k0 < K; k0 += 32) {
        gload16(gA0 + k0, &As[ar0][0]);
        gload16(gA1 + k0, &As[ar0 + 16][0]);
        gload16(gB0 + k0, &Bs[ar0][0]);
        gload16(gB1 + k0, &Bs[ar0 + 16][0]);
        __syncthreads();
        bf16x8 af[4], bfr[4];
        #pragma unroll
        for (int i = 0; i < 4; ++i) {
            af[i]  = *(const bf16x8*)(&As[wr + i * 16 + fr][ko]);
            bfr[i] = *(const bf16x8*)(&Bs[wc + i * 16 + fr][ko]);
        }
        #pragma unroll
        for (int i = 0; i < 4; ++i)
            #pragma unroll
            for (int j = 0; j < 4; ++j)
                acc[i][j] = __builtin_amdgcn_mfma_f32_16x16x32_bf16(af[i], bfr[j], acc[i][j], 0, 0, 0);
        __syncthreads();
    }
    const int cr = (lane >> 4) << 2, cc = lane & 15;
    #pragma unroll
    for (int i = 0; i < 4; ++i)
        #pragma unroll
        for (int j = 0; j < 4; ++j) {
            const int row0 = brow + wr + i * 16 + cr;
            const int col = bcol + wc + j * 16 + cc;
            #pragma unroll
            for (int r = 0; r < 4; ++r) {
                float v = acc[i][j][r];
                if (bias) v += bias[col];
                if (addend) v += addend[(size_t)(row0 + r) * N + col];
                C[(size_t)(row0 + r) * N + col] = v;
            }
        }
}

// ---------------- compose: per-token head math -> packed scan records + VB/G/SB ----------------
// record per (bh,t): 896B = bf16[5][64] {r, ksc, aa, bb, v} + f32[64] dec
__global__ __launch_bounds__(256) void compose_kernel(
    const float* __restrict__ RKV, const float* __restrict__ SM,
    const float* __restrict__ v_first, const float* __restrict__ k_first,
    const float* __restrict__ cosd, const float* __restrict__ sind,
    const float* __restrict__ R_bias, const float* __restrict__ K_bias,
    const float* __restrict__ V_bias, const float* __restrict__ w0,
    const float* __restrict__ a0, const float* __restrict__ v0b,
    const float* __restrict__ k0b, const float* __restrict__ ln_r,
    const float* __restrict__ ln_k, const float* __restrict__ r_k,
    char* __restrict__ SC, __hip_bfloat16* __restrict__ VB, float* __restrict__ SB,
    __hip_bfloat16* __restrict__ G) {
    __shared__ __align__(16) float rbuf[HN_];
    __shared__ __align__(16) float kbuf[KVD_];
    __shared__ __align__(16) float vbuf[KVD_];
    __shared__ float knorms[KVH_];
    __shared__ float cosb[64], sinb[64];
    const int bt = blockIdx.x;
    const int b = bt >> 10, t = bt & 1023;
    const int tid = threadIdx.x;
    const float* rkvrow = RKV + (size_t)bt * 3072;
    const float* smrow = SM + (size_t)bt * SMN;

    if (tid < 64) {
        cosb[tid] = cosd[(size_t)bt * 64 + tid];
        sinb[tid] = sind[(size_t)bt * 64 + tid];
    }

    const int h = tid >> 3;
    const int off = (tid & 7) << 3;
    const int n0 = tid << 3;
    float rraw[8];
    {
        float4 x0 = *(const float4*)(rkvrow + n0);
        float4 x1 = *(const float4*)(rkvrow + n0 + 4);
        float4 b0 = *(const float4*)(R_bias + n0);
        float4 b1 = *(const float4*)(R_bias + n0 + 4);
        rraw[0] = x0.x + b0.x; rraw[1] = x0.y + b0.y; rraw[2] = x0.z + b0.z; rraw[3] = x0.w + b0.w;
        rraw[4] = x1.x + b1.x; rraw[5] = x1.y + b1.y; rraw[6] = x1.z + b1.z; rraw[7] = x1.w + b1.w;
    }
    float rss = 0.f;
    #pragma unroll
    for (int j = 0; j < 8; ++j) { rss += rraw[j] * rraw[j]; rbuf[n0 + j] = rraw[j]; }
    rss += __shfl_xor(rss, 1); rss += __shfl_xor(rss, 2); rss += __shfl_xor(rss, 4);
    float rscale = rsqrtf(rss * (1.f / 64.f) + 1e-6f);

    const int kvh = tid >> 5;
    const int ko2 = (tid & 31) << 1;
    const int kidx = kvh * 64 + ko2;
    float kraw0 = rkvrow[2048 + kidx] + K_bias[kidx];
    float kraw1 = rkvrow[2048 + kidx + 1] + K_bias[kidx + 1];
    float kss = kraw0 * kraw0 + kraw1 * kraw1;
    kss += __shfl_xor(kss, 1); kss += __shfl_xor(kss, 2); kss += __shfl_xor(kss, 4);
    kss += __shfl_xor(kss, 8); kss += __shfl_xor(kss, 16);
    float kscale = rsqrtf(kss * (1.f / 64.f) + 1e-6f);
    kbuf[kidx] = kraw0; kbuf[kidx + 1] = kraw1;

    {
        float va = rkvrow[2560 + kidx] + V_bias[kidx];
        float vb2 = rkvrow[2560 + kidx + 1] + V_bias[kidx + 1];
        float gv0 = sigmf(smrow[4096 + kidx] + v0b[kidx]);
        float gv1 = sigmf(smrow[4096 + kidx + 1] + v0b[kidx + 1]);
        vbuf[kidx] = va + (v_first[(size_t)bt * 512 + kidx] - va) * gv0;
        vbuf[kidx + 1] = vb2 + (v_first[(size_t)bt * 512 + kidx + 1] - vb2) * gv1;
    }
    __syncthreads();

    float rf[8];
    #pragma unroll
    for (int j = 0; j < 8; ++j) {
        int nn = off + j;
        int nn2 = (nn + 32) & 63;
        float val = rbuf[h * 64 + nn] * rscale * ln_r[nn];
        float oth = rbuf[h * 64 + nn2] * rscale * ln_r[nn2];
        float rot = (nn < 32) ? -oth : oth;
        rf[j] = val * cosb[nn] + rot * sinb[nn];
    }
    float kfv[2];
    #pragma unroll
    for (int j = 0; j < 2; ++j) {
        int nn = ko2 + j;
        int nn2 = (nn + 32) & 63;
        float val = kbuf[kvh * 64 + nn] * kscale * ln_k[nn];
        float oth = kbuf[kvh * 64 + nn2] * kscale * ln_k[nn2];
        float rot = (nn < 32) ? -oth : oth;
        float kr = val * cosb[nn] + rot * sinb[nn];
        float gk = sigmf(smrow[6656 + kvh * 64 + nn] + k0b[kvh * 64 + nn]);
        kfv[j] = kr + (k_first[(size_t)bt * 512 + kvh * 64 + nn] - kr) * gk;
    }
    __syncthreads();
    kbuf[kidx] = kfv[0]; kbuf[kidx + 1] = kfv[1];
    float kn = kfv[0] * kfv[0] + kfv[1] * kfv[1];
    kn += __shfl_xor(kn, 1); kn += __shfl_xor(kn, 2); kn += __shfl_xor(kn, 4);
    kn += __shfl_xor(kn, 8); kn += __shfl_xor(kn, 16);
    if ((tid & 31) == 0) knorms[kvh] = fmaxf(sqrtf(kn), 1e-12f);
    __syncthreads();

    const float knv = knorms[h >> 2];
    char* scb = SC + ((size_t)(b * H_ + h) * T_ + t) * 896;
    __hip_bfloat16* us = (__hip_bfloat16*)scb;
    float* df = (float*)(scb + 640);
    float4 w1a = *(const float4*)(smrow + n0);
    float4 w1b = *(const float4*)(smrow + n0 + 4);
    float4 ara = *(const float4*)(smrow + 2048 + n0);
    float4 arb = *(const float4*)(smrow + 2048 + n0 + 4);
    float4 ga  = *(const float4*)(smrow + 4608 + n0);
    float4 gb  = *(const float4*)(smrow + 4608 + n0 + 4);
    float w1arr[8] = {w1a.x, w1a.y, w1a.z, w1a.w, w1b.x, w1b.y, w1b.z, w1b.w};
    float aarr[8] = {ara.x, ara.y, ara.z, ara.w, arb.x, arb.y, arb.z, arb.w};
    float garr[8] = {ga.x, ga.y, ga.z, ga.w, gb.x, gb.y, gb.z, gb.w};
    float bsum = 0.f;
    #pragma unroll
    for (int j = 0; j < 8; ++j) {
        int nn = off + j, n = n0 + j;
        float w1 = w1arr[j] + w0[n];
        float w2v = -log1pf(expf(-w1)) - 0.5f;
        float av = sigmf(aarr[j] + a0[n]);
        float dec = expf(-expf(w2v));
        float kb = kbuf[(h >> 2) * 64 + nn];
        float vbv = vbuf[(h >> 2) * 64 + nn];
        float kkv = kb / knv;
        float ksc = kb * (1.f - w2v + av);
        us[nn]       = __float2bfloat16(rf[j]);
        us[64 + nn]  = __float2bfloat16(ksc);
        us[128 + nn] = __float2bfloat16(-kkv);
        us[192 + nn] = __float2bfloat16(kkv * av);
        us[256 + nn] = __float2bfloat16(vbv);
        df[nn] = dec;
        VB[(size_t)bt * HN_ + n] = __float2bfloat16(vbv);
        G[(size_t)bt * HN_ + n] = __float2bfloat16(garr[j]);
        bsum += rf[j] * ksc * r_k[h * 64 + nn];
    }
    bsum += __shfl_xor(bsum, 1); bsum += __shfl_xor(bsum, 2); bsum += __shfl_xor(bsum, 4);
    if ((tid & 7) == 0) SB[bt * H_ + h] = bsum;
}

// ---------------- chunked scan pass 1 (4-wave unified, QUAD-step batching) ----------------
// wave w owns rows [16w,16w+16) of BOTH P and S; lane owns 16 cols of one row (4+4 f32x4).
// LDS stages FOUR steps per barrier (double-buffered): 1 barrier / 4 steps, barrier-free
// 4-step compute runs let DS reads of steps t+1..t+3 hide under step t's serial FMA chain.
#define P1_LOAD(tt, s) do { \
    const __hip_bfloat16* us_ = (const __hip_bfloat16*)(base + (size_t)(tt) * 896); \
    if (wid == 0)      { p0[s] = __bfloat162float(us_[128 + lane]); p1[s] = __bfloat162float(us_[lane]); } \
    else if (wid == 1) { p0[s] = __bfloat162float(us_[192 + lane]); p1[s] = __bfloat162float(us_[256 + lane]); } \
    else if (wid == 2) { p0[s] = *(const float*)(base + (size_t)(tt) * 896 + 640 + 4 * lane); } \
    else               { p0[s] = __bfloat162float(us_[64 + lane]); } \
} while (0)

__global__ __launch_bounds__(256) void scan_pass1(
    const char* __restrict__ SC, float* __restrict__ Q, float* __restrict__ O,
    float* __restrict__ Pf, float* __restrict__ Sf) {
    const int chunk = blockIdx.x;
    const int bh = chunk >> 4, c = chunk & 15;
    const int b = bh >> 5, h = bh & 31;
    const int tid = threadIdx.x;
    const int wid = tid >> 6, lane = tid & 63;
    const int cq = lane >> 4;            // col quarter
    const int cb = cq << 4;              // col base
    const int row = (wid << 4) + (lane & 15);
    const char* base = SC + ((size_t)bh * T_ + (size_t)c * CH) * 896;
    __shared__ __align__(16) float ld[2][4][6][64];  // [buf][slot][0=a 1=b 2=d 3=k 4=r 5=v][lane]

    f32x4 P4[4], S4[4];
    #pragma unroll
    for (int j = 0; j < 4; ++j)
        #pragma unroll
        for (int e = 0; e < 4; ++e) {
            P4[j][e] = (cb + 4 * j + e == row) ? 1.f : 0.f;
            S4[j][e] = 0.f;
        }

    float p0[4], p1[4];
    P1_LOAD(0, 0); P1_LOAD(1, 1); P1_LOAD(2, 2); P1_LOAD(3, 3);
    float* qrow = Q + (size_t)chunk * CH * 64 + row;
    float* orow = O + ((size_t)b * T_ + (size_t)c * CH) * HN_ + h * 64 + row;
    for (int q = 0; q < CH / 4; ++q) {
        const int buf = q & 1;
        const int tbase = q << 2;
        // stage this quad's vectors (from ring regs loaded one quad ago)
        #pragma unroll
        for (int s = 0; s < 4; ++s) {
            if (wid == 0)      { ld[buf][s][0][lane] = p0[s]; ld[buf][s][4][lane] = p1[s]; }
            else if (wid == 1) { ld[buf][s][1][lane] = p0[s]; ld[buf][s][5][lane] = p1[s]; }
            else if (wid == 2) { ld[buf][s][2][lane] = p0[s]; }
            else               { ld[buf][s][3][lane] = p0[s]; }
        }
        __syncthreads();
        // prefetch next quad into the ring
        if (q + 1 < CH / 4) {
            P1_LOAD(tbase + 4, 0); P1_LOAD(tbase + 5, 1);
            P1_LOAD(tbase + 6, 2); P1_LOAD(tbase + 7, 3);
        }
        // 4 steps, no barriers
        #pragma unroll
        for (int s = 0; s < 4; ++s) {
            const int t = tbase + s;
            f32x4 a4[4];
            #pragma unroll
            for (int j = 0; j < 4; ++j) a4[j] = *(const f32x4*)&ld[buf][s][0][cb + 4 * j];
            f32x4 dpv = {0,0,0,0}, dsv = {0,0,0,0};
            #pragma unroll
            for (int j = 0; j < 4; ++j) { dpv += P4[j] * a4[j]; dsv += S4[j] * a4[j]; }
            float dp = dpv[0] + dpv[1] + dpv[2] + dpv[3];
            float dsd = dsv[0] + dsv[1] + dsv[2] + dsv[3];
            dp += __shfl_xor(dp, 16);  dp += __shfl_xor(dp, 32);
            dsd += __shfl_xor(dsd, 16); dsd += __shfl_xor(dsd, 32);
            const float vt = ld[buf][s][5][row];
            const f32x4 cPv = {dp, dp, dp, dp}, sav = {dsd, dsd, dsd, dsd}, vtv = {vt, vt, vt, vt};
            f32x4 qp = {0,0,0,0}, op = {0,0,0,0};
            #pragma unroll
            for (int j = 0; j < 4; ++j) {
                f32x4 d4 = *(const f32x4*)&ld[buf][s][2][cb + 4 * j];
                f32x4 b4 = *(const f32x4*)&ld[buf][s][1][cb + 4 * j];
                f32x4 k4 = *(const f32x4*)&ld[buf][s][3][cb + 4 * j];
                f32x4 r4 = *(const f32x4*)&ld[buf][s][4][cb + 4 * j];
                f32x4 Pn = P4[j] * d4 + cPv * b4;
                f32x4 Sn = S4[j] * d4 + sav * b4 + vtv * k4;
                P4[j] = Pn; S4[j] = Sn;
                qp += Pn * r4; op += Sn * r4;
            }
            float qs = qp[0] + qp[1] + qp[2] + qp[3];
            float os = op[0] + op[1] + op[2] + op[3];
            qs += __shfl_xor(qs, 16); qs += __shfl_xor(qs, 32);
            os += __shfl_xor(os, 16); os += __shfl_xor(os, 32);
            if (cq == 0) {
                qrow[(size_t)t * 64] = qs;
                orow[(size_t)t * HN_] = os;   // oloc, unscaled
            }
        }
    }
    float* pf = Pf + (size_t)chunk * 4096 + (size_t)row * 64 + cb;
    float* sf = Sf + (size_t)chunk * 4096 + (size_t)row * 64 + cb;
    #pragma unroll
    for (int j = 0; j < 4; ++j) {
        *(f32x4*)(pf + 4 * j) = P4[j];
        *(f32x4*)(sf + 4 * j) = S4[j];
    }
}

// ---------------- pass 2: propagate chunk-initial states (Sf -> Sinit in place) ----------------
__global__ __launch_bounds__(256) void scan_pass2(
    const float* __restrict__ Pf, float* __restrict__ Sf, const float* __restrict__ state) {
    const int blk = blockIdx.x;
    const int bh = blk >> 2, rb = blk & 3;
    const int tid = threadIdx.x;
    const int lv = tid >> 4, c0 = (tid & 15) << 2;
    __shared__ __align__(16) float S[16][68];
    __shared__ __align__(16) float P[64][64];

    *(f32x4*)&S[lv][c0] = *(const f32x4*)&state[(size_t)bh * 4096 + 1024 * rb + tid * 4];
    const size_t pbase = (size_t)(bh * NCH) * 4096;
    {
        f32x4 p0[4];
        #pragma unroll
        for (int j = 0; j < 4; ++j) p0[j] = *(const f32x4*)&Pf[pbase + tid * 16 + 4 * j];
        #pragma unroll
        for (int j = 0; j < 4; ++j) *(f32x4*)(&P[0][0] + tid * 16 + 4 * j) = p0[j];
    }
    __syncthreads();

    for (int c = 0; c < NCH; ++c) {
        const size_t ck = (size_t)(bh * NCH + c) * 4096;
        f32x4 pp[4];
        if (c + 1 < NCH) {
            #pragma unroll
            for (int j = 0; j < 4; ++j) pp[j] = *(const f32x4*)&Pf[ck + 4096 + tid * 16 + 4 * j];
        }
        f32x4 acc = *(const f32x4*)&Sf[ck + 1024 * rb + tid * 4];   // S_loc(c)
        f32x4 cur = *(const f32x4*)&S[lv][c0];                      // Sinit(c)
        #pragma unroll 4
        for (int k4 = 0; k4 < 64; k4 += 4) {
            f32x4 sk4 = *(const f32x4*)&S[lv][k4];
            #pragma unroll
            for (int kk = 0; kk < 4; ++kk) {
                f32x4 pr = *(const f32x4*)&P[k4 + kk][c0];
                f32x4 sv = {sk4[kk], sk4[kk], sk4[kk], sk4[kk]};
                acc += sv * pr;
            }
        }
        __syncthreads();
        *(f32x4*)&S[lv][c0] = acc;
        if (c + 1 < NCH) {
            #pragma unroll
            for (int j = 0; j < 4; ++j) *(f32x4*)(&P[0][0] + tid * 16 + 4 * j) = pp[j];
        }
        *(f32x4*)&Sf[ck + 1024 * rb + tid * 4] = cur;
        __syncthreads();
    }
}

// ---------------- pass 3 + post fused: u = ((Sinit·q + oloc)·N^-0.5 + SB·VB)·G -> bf16 ----------------
__global__ __launch_bounds__(64) void pass3_post(
    const float* __restrict__ Q, const float* __restrict__ Sinit, const float* __restrict__ OL,
    const float* __restrict__ SB, const __hip_bfloat16* __restrict__ VB,
    const __hip_bfloat16* __restrict__ G, __hip_bfloat16* __restrict__ Ub) {
    const int chunk = blockIdx.x;
    const int bh = chunk >> 4, c = chunk & 15;
    const int b = bh >> 5, h = bh & 31;
    const int t = threadIdx.x;
    __shared__ __align__(16) float S[64][64];
    #pragma unroll
    for (int j = 0; j < 16; ++j)
        *(f32x4*)&S[t][4 * j] = *(const f32x4*)&Sinit[(size_t)chunk * 4096 + (size_t)t * 64 + 4 * j];
    __syncthreads();
    float q[64];
    #pragma unroll
    for (int j = 0; j < 16; ++j)
        *(f32x4*)&q[4 * j] = *(const f32x4*)&Q[((size_t)chunk * CH + t) * 64 + 4 * j];
    const size_t bt = (size_t)b * T_ + (size_t)c * CH + t;
    const float sb = SB[bt * H_ + h];
    const float* olrow = OL + bt * HN_ + h * 64;
    const __hip_bfloat16* vbrow = VB + bt * HN_ + h * 64;
    const __hip_bfloat16* grow = G + bt * HN_ + h * 64;
    __hip_bfloat16* urow = Ub + bt * HN_ + h * 64;
    #pragma unroll 4
    for (int v = 0; v < 64; ++v) {
        f32x4 a = {0, 0, 0, 0};
        #pragma unroll
        for (int j = 0; j < 16; ++j)
            a += *(const f32x4*)&S[v][4 * j] * *(const f32x4*)&q[4 * j];
        float o = (a[0] + a[1] + a[2] + a[3] + olrow[v]) * 0.125f;
        float u = (o + sb * __bfloat162float(vbrow[v])) * __bfloat162float(grow[v]);
        urow[v] = __float2bfloat16(u);
    }
}

extern "C" void kernel_launch(void* const* d_in, const int* in_sizes, int n_in,
                              void* d_out, int out_size, void* d_ws, size_t ws_size,
                              hipStream_t stream) {
    (void)in_sizes; (void)n_in; (void)out_size; (void)ws_size;
    const float* x_in    = (const float*)d_in[0];
    const float* v_first = (const float*)d_in[1];
    const float* k_first = (const float*)d_in[2];
    const float* state   = (const float*)d_in[3];
    const float* calc_cos= (const float*)d_in[4];
    const float* calc_sin= (const float*)d_in[5];
    const float* wavgk1  = (const float*)d_in[6];
    const float* w0      = (const float*)d_in[7];
    const float* w2      = (const float*)d_in[8];
    const float* a0      = (const float*)d_in[9];
    const float* a2      = (const float*)d_in[10];
    const float* v0      = (const float*)d_in[11];
    const float* v2      = (const float*)d_in[12];
    const float* g2      = (const float*)d_in[13];
    const float* k0      = (const float*)d_in[14];
    const float* k2      = (const float*)d_in[15];
    const float* r_k     = (const float*)d_in[16];
    const float* RKV_w   = (const float*)d_in[17];
    const float* O_w     = (const float*)d_in[18];
    const float* R_bias  = (const float*)d_in[19];
    const float* K_bias  = (const float*)d_in[20];
    const float* V_bias  = (const float*)d_in[21];
    const float* O_bias  = (const float*)d_in[22];
    const float* ln_r    = (const float*)d_in[23];
    const float* ln_k    = (const float*)d_in[24];
    const float* ln1     = (const float*)d_in[25];
    float* out = (float*)d_out;

    char* ws = (char*)d_ws;
    size_t off = 0;
    auto alloc = [&](size_t bytes) -> char* {
        char* p = ws + off;
        off = (off + bytes + 255) & ~(size_t)255;
        return p;
    };
    // ---- persistent region (~101 MB) ----
    char*  SCb = alloc((size_t)64 * T_ * 896);                        // compose -> pass1
    __hip_bfloat16* Ub = (__hip_bfloat16*)SCb;                        // aliases SCb (pass3 -> final gemm)
    __hip_bfloat16* VBb = (__hip_bfloat16*)alloc((size_t)MTOK * HN_ * 2); // compose -> pass3
    __hip_bfloat16* Gb  = (__hip_bfloat16*)alloc((size_t)MTOK * HN_ * 2); // compose -> pass3
    float* SBf = (float*)alloc((size_t)MTOK * H_ * 4);                // compose -> pass3
    float* Of  = (float*)alloc((size_t)MTOK * HN_ * 4);               // pass1 -> pass3 (oloc)
    __hip_bfloat16* OWb = (__hip_bfloat16*)alloc((size_t)2048 * 2048 * 2); // prep -> final gemm

    // ---- overlapped region: stage A (pre-scan, ~123 MB) ----
    size_t ovl = off;
    float* SMf = (float*)alloc((size_t)MTOK * SMN * 4);               // gemm3 -> compose
    __hip_bfloat16* Xb     = (__hip_bfloat16*)alloc((size_t)MTOK * HN_ * 2);
    __hip_bfloat16* RKVb   = (__hip_bfloat16*)alloc((size_t)3072 * 2048 * 2);
    __hip_bfloat16* WT1b   = (__hip_bfloat16*)alloc((size_t)320 * 2048 * 2);
    __hip_bfloat16* Wcatb  = (__hip_bfloat16*)alloc((size_t)SMN * KCAT * 2);
    __hip_bfloat16* XWmodb = (__hip_bfloat16*)alloc((size_t)MTOK * KCAT * 2);
    float* RKVf  = (float*)alloc((size_t)MTOK * 3072 * 4);
    float* XWp   = (float*)alloc((size_t)4 * MTOK * KCAT * 4);        // split-K partials
    // ---- overlapped region: stage B (scan, ~50 MB) — reuses stage A space ----
    off = ovl;
    float* Qf  = (float*)alloc((size_t)NCHUNK * CH * 64 * 4);         // pass1 -> pass3
    float* Pff = (float*)alloc((size_t)NCHUNK * 4096 * 4);            // pass1 -> pass2
    float* Sff = (float*)alloc((size_t)NCHUNK * 4096 * 4);            // pass1 -> pass3

    // merged weight prep
    {
        long total = (long)PREP_N1 + PREP_N2 + PREP_N3 + PREP_N4;
        prep_kernel<<<(int)((total + 255) / 256), 256, 0, stream>>>(
            RKV_w, O_w, wavgk1, w2, a2, v2, g2, k2, RKVb, OWb, WT1b, Wcatb);
    }

    // x = rmsnorm(x_in, ln1) -> bf16
    rmsnorm_kernel<<<MTOK, 256, 0, stream>>>(x_in, ln1, Xb);

    // big GEMMs (global_load_lds 128-tile)
    gemm_bt128<<<dim3(3072 / 128, MTOK / 128), 256, 0, stream>>>(Xb, RKVb, RKVf, MTOK, 3072, 2048, nullptr, nullptr);
    gemm_xw_sk<<<dim3(KCAT / 64, MTOK / 64, 4), 256, 0, stream>>>(Xb, WT1b, XWp, MTOK, KCAT, 2048);
    xw_reduce<<<(MTOK * KCAT + 255) / 256, 256, 0, stream>>>(XWp, XWmodb);
    gemm_bt128<<<dim3(SMN / 128, MTOK / 128), 256, 0, stream>>>(XWmodb, Wcatb, SMf, MTOK, SMN, KCAT, nullptr, nullptr);

    // compose scan records (+ G gate, VB, SB)
    compose_kernel<<<MTOK, 256, 0, stream>>>(RKVf, SMf, v_first, k_first, calc_cos, calc_sin,
                                             R_bias, K_bias, V_bias, w0, a0, v0, k0,
                                             ln_r, ln_k, r_k, SCb, VBb, SBf, Gb);

    // chunked RWKV scan: pass1 (quad-batched) -> pass2 (chunk-sequential) -> pass3+post
    scan_pass1<<<NCHUNK, 256, 0, stream>>>(SCb, Qf, Of, Pff, Sff);
    scan_pass2<<<B_ * H_ * 4, 256, 0, stream>>>(Pff, Sff, state);
    pass3_post<<<NCHUNK, 64, 0, stream>>>(Qf, Sff, Of, SBf, VBb, Gb, Ub);

    // output GEMM (adds x_in and O_bias in epilogue)
    gemm_bt128<<<dim3(HN_ / 128, MTOK / 128), 256, 0, stream>>>(Ub, OWb, out, MTOK, HN_, 2048, O_bias, x_in);
}

// Round 13
// 412.824 us; speedup vs baseline: 1.0191x; 1.0191x over previous
//
#include <hip/hip_runtime.h>
#include <hip/hip_bf16.h>
#include <stdint.h>

// Problem constants
#define B_ 2
#define T_ 1024
#define H_ 32
#define N_ 64
#define HN_ 2048
#define KVH_ 8
#define KVD_ 512
#define MTOK 2048        // B*T
#define SMN 7168         // concat small-gemm output width
#define KCAT 320
#define CH 64            // scan chunk length
#define NCH 16           // T/CH
#define NCHUNK 1024      // B*H*NCH

typedef __bf16 bf16x8 __attribute__((ext_vector_type(8)));
typedef float f32x4 __attribute__((ext_vector_type(4)));

typedef __attribute__((address_space(1))) uint32_t gu32;
typedef __attribute__((address_space(3))) uint32_t lu32;
__device__ __forceinline__ void gload16(const void* g, void* l) {
    __builtin_amdgcn_global_load_lds((gu32*)g, (lu32*)l, 16, 0, 0);
}

__device__ __forceinline__ float sigmf(float x) { return 1.f / (1.f + expf(-x)); }

// ---------------- merged prep kernel: f2b(RKV_w) | f2b(O_w) | transpose(wavgk1) | wcat ----------------
#define PREP_N1 (3072 * 2048)
#define PREP_N2 (2048 * 2048)
#define PREP_N3 (320 * 2048)
#define PREP_N4 (SMN * KCAT)
__global__ void prep_kernel(const float* __restrict__ RKV_w, const float* __restrict__ O_w,
                            const float* __restrict__ wavgk1,
                            const float* __restrict__ w2, const float* __restrict__ a2,
                            const float* __restrict__ v2, const float* __restrict__ g2,
                            const float* __restrict__ k2,
                            __hip_bfloat16* __restrict__ RKVb, __hip_bfloat16* __restrict__ OWb,
                            __hip_bfloat16* __restrict__ WT1b, __hip_bfloat16* __restrict__ Wcatb) {
    long i = (long)blockIdx.x * 256 + threadIdx.x;
    if (i < PREP_N1) { RKVb[i] = __float2bfloat16(RKV_w[i]); return; }
    i -= PREP_N1;
    if (i < PREP_N2) { OWb[i] = __float2bfloat16(O_w[i]); return; }
    i -= PREP_N2;
    if (i < PREP_N3) {
        int c = (int)(i / 2048), r = (int)(i % 2048);
        WT1b[i] = __float2bfloat16(wavgk1[(size_t)r * 320 + c]);
        return;
    }
    i -= PREP_N3;
    if (i >= PREP_N4) return;
    int j = (int)(i / KCAT), k = (int)(i % KCAT);
    float v = 0.f;
    if (j < 2048)      { if (k < 64)             v = w2[(size_t)k * 2048 + j]; }
    else if (j < 4096) { if (k >= 64 && k < 128)  v = a2[(size_t)(k - 64) * 2048 + (j - 2048)]; }
    else if (j < 4608) { if (k >= 128 && k < 160) v = v2[(size_t)(k - 128) * 512 + (j - 4096)]; }
    else if (j < 6656) { if (k >= 160 && k < 288) v = g2[(size_t)(k - 160) * 2048 + (j - 4608)]; }
    else               { if (k >= 288)            v = k2[(size_t)(k - 288) * 512 + (j - 6656)]; }
    Wcatb[i] = __float2bfloat16(v);
}

// ---------------- RMSNorm over HN per token -> bf16 ----------------
__global__ __launch_bounds__(256) void rmsnorm_kernel(const float* __restrict__ x,
                                                      const float* __restrict__ ln1,
                                                      __hip_bfloat16* __restrict__ out) {
    const int bt = blockIdx.x, tid = threadIdx.x;
    const float* row = x + (size_t)bt * HN_;
    float4 v0 = *(const float4*)(row + tid * 8);
    float4 v1 = *(const float4*)(row + tid * 8 + 4);
    float s = v0.x*v0.x + v0.y*v0.y + v0.z*v0.z + v0.w*v0.w
            + v1.x*v1.x + v1.y*v1.y + v1.z*v1.z + v1.w*v1.w;
    for (int m = 1; m < 64; m <<= 1) s += __shfl_xor(s, m);
    __shared__ float red[4];
    if ((tid & 63) == 0) red[tid >> 6] = s;
    __syncthreads();
    s = red[0] + red[1] + red[2] + red[3];
    float scale = rsqrtf(s * (1.f / HN_) + 1e-6f);
    float vals[8] = {v0.x, v0.y, v0.z, v0.w, v1.x, v1.y, v1.z, v1.w};
    __align__(16) __hip_bfloat16 tmp[8];
    #pragma unroll
    for (int j = 0; j < 8; ++j)
        tmp[j] = __float2bfloat16(vals[j] * scale * ln1[tid * 8 + j]);
    *(uint4*)&out[(size_t)bt * HN_ + tid * 8] = *(const uint4*)tmp;
}

// ---------------- split-K 64-tile GEMM for XW (N=320): partial f32 out ----------------
__global__ __launch_bounds__(256) void gemm_xw_sk(const __hip_bfloat16* __restrict__ A,
                                                  const __hip_bfloat16* __restrict__ B,
                                                  float* __restrict__ Cp, int M, int N, int K) {
    __shared__ __align__(16) __hip_bfloat16 As[64][40];
    __shared__ __align__(16) __hip_bfloat16 Bs[64][40];
    const int tid = threadIdx.x;
    const int wave = tid >> 6, lane = tid & 63;
    const int wr = (wave >> 1) * 32, wc = (wave & 1) * 32;
    const int brow = blockIdx.y << 6, bcol = blockIdx.x << 6;
    const int z = blockIdx.z;
    const int kbeg = z * (K >> 2), kend = kbeg + (K >> 2);
    const int lrow = tid >> 2, lcol = (tid & 3) << 3;
    const int fr = lane & 15, ko = (lane >> 4) << 3;
    f32x4 acc[2][2] = {};
    for (int k0 = kbeg; k0 < kend; k0 += 32) {
        uint4 av = *(const uint4*)(A + (size_t)(brow + lrow) * K + k0 + lcol);
        uint4 bv = *(const uint4*)(B + (size_t)(bcol + lrow) * K + k0 + lcol);
        *(uint4*)(&As[lrow][lcol]) = av;
        *(uint4*)(&Bs[lrow][lcol]) = bv;
        __syncthreads();
        bf16x8 af0 = *(const bf16x8*)(&As[wr + fr][ko]);
        bf16x8 af1 = *(const bf16x8*)(&As[wr + 16 + fr][ko]);
        bf16x8 bf0 = *(const bf16x8*)(&Bs[wc + fr][ko]);
        bf16x8 bf1 = *(const bf16x8*)(&Bs[wc + 16 + fr][ko]);
        acc[0][0] = __builtin_amdgcn_mfma_f32_16x16x32_bf16(af0, bf0, acc[0][0], 0, 0, 0);
        acc[0][1] = __builtin_amdgcn_mfma_f32_16x16x32_bf16(af0, bf1, acc[0][1], 0, 0, 0);
        acc[1][0] = __builtin_amdgcn_mfma_f32_16x16x32_bf16(af1, bf0, acc[1][0], 0, 0, 0);
        acc[1][1] = __builtin_amdgcn_mfma_f32_16x16x32_bf16(af1, bf1, acc[1][1], 0, 0, 0);
        __syncthreads();
    }
    const int cr = (lane >> 4) << 2, cc = lane & 15;
    float* Cz = Cp + (size_t)z * M * N;
    #pragma unroll
    for (int i = 0; i < 2; ++i)
        #pragma unroll
        for (int j = 0; j < 2; ++j)
            #pragma unroll
            for (int r = 0; r < 4; ++r) {
                int row = brow + wr + i * 16 + cr + r;
                int col = bcol + wc + j * 16 + cc;
                Cz[(size_t)row * N + col] = acc[i][j][r];
            }
}

// ---------------- reduce split-K partials + xw activation -> bf16 ----------------
__global__ void xw_reduce(const float* __restrict__ Cp, __hip_bfloat16* __restrict__ out) {
    long i = (long)blockIdx.x * 256 + threadIdx.x;
    if (i >= (long)MTOK * KCAT) return;
    const long MN = (long)MTOK * KCAT;
    float v = Cp[i] + Cp[i + MN] + Cp[i + 2 * MN] + Cp[i + 3 * MN];
    int c = (int)(i % KCAT);
    if (c < 64) v = tanhf(v);
    else if (c >= 160 && c < 288) v = sigmf(v);
    out[i] = __float2bfloat16(v);
}

// ---------------- 128-tile MFMA GEMM, global_load_lds staging + XCD-aware block swizzle ----------------
// 1D grid, nwg % 8 == 0 required (384/896/256 all satisfy).
__global__ __launch_bounds__(256) void gemm_bt128(const __hip_bfloat16* __restrict__ A,
                                                  const __hip_bfloat16* __restrict__ B,
                                                  float* __restrict__ C, int M, int N, int K,
                                                  const float* __restrict__ bias,
                                                  const float* __restrict__ addend) {
    __shared__ __align__(16) __hip_bfloat16 As[128][32];
    __shared__ __align__(16) __hip_bfloat16 Bs[128][32];
    const int nwg = gridDim.x;
    int wg = blockIdx.x;
    wg = (wg & 7) * (nwg >> 3) + (wg >> 3);     // XCD swizzle (bijective: nwg%8==0)
    const int nx = N >> 7;
    const int bx = wg % nx, by = wg / nx;
    const int brow = by << 7, bcol = bx << 7;
    const int tid = threadIdx.x;
    const int wave = tid >> 6, lane = tid & 63;
    const int wr = (wave >> 1) * 64, wc = (wave & 1) * 64;
    const int fr = lane & 15, ko = (lane >> 4) << 3;
    const int ar0 = wave * 32;            // wave's staging row block
    const int sr = lane >> 2;             // row within 16-row group
    const int sc = (lane & 3) << 3;       // k-elem offset (8 elems = 16 B)
    f32x4 acc[4][4] = {};
    const __hip_bfloat16* gA0 = A + (size_t)(brow + ar0 + sr) * K + sc;
    const __hip_bfloat16* gA1 = A + (size_t)(brow + ar0 + 16 + sr) * K + sc;
    const __hip_bfloat16* gB0 = B + (size_t)(bcol + ar0 + sr) * K + sc;
    const __hip_bfloat16* gB1 = B + (size_t)(bcol + ar0 + 16 + sr) * K + sc;
    for (int k0 = 0; k0 < K; k0 += 32) {
        gload16(gA0 + k0, &As[ar0][0]);
        gload16(gA1 + k0, &As[ar0 + 16][0]);
        gload16(gB0 + k0, &Bs[ar0][0]);
        gload16(gB1 + k0, &Bs[ar0 + 16][0]);
        __syncthreads();
        bf16x8 af[4], bfr[4];
        #pragma unroll
        for (int i = 0; i < 4; ++i) {
            af[i]  = *(const bf16x8*)(&As[wr + i * 16 + fr][ko]);
            bfr[i] = *(const bf16x8*)(&Bs[wc + i * 16 + fr][ko]);
        }
        #pragma unroll
        for (int i = 0; i < 4; ++i)
            #pragma unroll
            for (int j = 0; j < 4; ++j)
                acc[i][j] = __builtin_amdgcn_mfma_f32_16x16x32_bf16(af[i], bfr[j], acc[i][j], 0, 0, 0);
        __syncthreads();
    }
    const int cr = (lane >> 4) << 2, cc = lane & 15;
    #pragma unroll
    for (int i = 0; i < 4; ++i)
        #pragma unroll
        for (int j = 0; j < 4; ++j) {
            const int row0 = brow + wr + i * 16 + cr;
            const int col = bcol + wc + j * 16 + cc;
            #pragma unroll
            for (int r = 0; r < 4; ++r) {
                float v = acc[i][j][r];
                if (bias) v += bias[col];
                if (addend) v += addend[(size_t)(row0 + r) * N + col];
                C[(size_t)(row0 + r) * N + col] = v;
            }
        }
}

// ---------------- compose: per-token head math -> packed scan records + VB/G/SB ----------------
// record per (bh,t): 896B = bf16[5][64] {r, ksc, aa, bb, v} + f32[64] dec. Vectorized 16B stores.
__global__ __launch_bounds__(256) void compose_kernel(
    const float* __restrict__ RKV, const float* __restrict__ SM,
    const float* __restrict__ v_first, const float* __restrict__ k_first,
    const float* __restrict__ cosd, const float* __restrict__ sind,
    const float* __restrict__ R_bias, const float* __restrict__ K_bias,
    const float* __restrict__ V_bias, const float* __restrict__ w0,
    const float* __restrict__ a0, const float* __restrict__ v0b,
    const float* __restrict__ k0b, const float* __restrict__ ln_r,
    const float* __restrict__ ln_k, const float* __restrict__ r_k,
    char* __restrict__ SC, __hip_bfloat16* __restrict__ VB, float* __restrict__ SB,
    __hip_bfloat16* __restrict__ G) {
    __shared__ __align__(16) float rbuf[HN_];
    __shared__ __align__(16) float kbuf[KVD_];
    __shared__ __align__(16) float vbuf[KVD_];
    __shared__ float knorms[KVH_];
    __shared__ float cosb[64], sinb[64];
    const int bt = blockIdx.x;
    const int b = bt >> 10, t = bt & 1023;
    const int tid = threadIdx.x;
    const float* rkvrow = RKV + (size_t)bt * 3072;
    const float* smrow = SM + (size_t)bt * SMN;

    if (tid < 64) {
        cosb[tid] = cosd[(size_t)bt * 64 + tid];
        sinb[tid] = sind[(size_t)bt * 64 + tid];
    }

    const int h = tid >> 3;
    const int off = (tid & 7) << 3;
    const int n0 = tid << 3;
    float rraw[8];
    {
        float4 x0 = *(const float4*)(rkvrow + n0);
        float4 x1 = *(const float4*)(rkvrow + n0 + 4);
        float4 b0 = *(const float4*)(R_bias + n0);
        float4 b1 = *(const float4*)(R_bias + n0 + 4);
        rraw[0] = x0.x + b0.x; rraw[1] = x0.y + b0.y; rraw[2] = x0.z + b0.z; rraw[3] = x0.w + b0.w;
        rraw[4] = x1.x + b1.x; rraw[5] = x1.y + b1.y; rraw[6] = x1.z + b1.z; rraw[7] = x1.w + b1.w;
    }
    float rss = 0.f;
    #pragma unroll
    for (int j = 0; j < 8; ++j) { rss += rraw[j] * rraw[j]; rbuf[n0 + j] = rraw[j]; }
    rss += __shfl_xor(rss, 1); rss += __shfl_xor(rss, 2); rss += __shfl_xor(rss, 4);
    float rscale = rsqrtf(rss * (1.f / 64.f) + 1e-6f);

    const int kvh = tid >> 5;
    const int ko2 = (tid & 31) << 1;
    const int kidx = kvh * 64 + ko2;
    float kraw0 = rkvrow[2048 + kidx] + K_bias[kidx];
    float kraw1 = rkvrow[2048 + kidx + 1] + K_bias[kidx + 1];
    float kss = kraw0 * kraw0 + kraw1 * kraw1;
    kss += __shfl_xor(kss, 1); kss += __shfl_xor(kss, 2); kss += __shfl_xor(kss, 4);
    kss += __shfl_xor(kss, 8); kss += __shfl_xor(kss, 16);
    float kscale = rsqrtf(kss * (1.f / 64.f) + 1e-6f);
    kbuf[kidx] = kraw0; kbuf[kidx + 1] = kraw1;

    {
        float va = rkvrow[2560 + kidx] + V_bias[kidx];
        float vb2 = rkvrow[2560 + kidx + 1] + V_bias[kidx + 1];
        float gv0 = sigmf(smrow[4096 + kidx] + v0b[kidx]);
        float gv1 = sigmf(smrow[4096 + kidx + 1] + v0b[kidx + 1]);
        vbuf[kidx] = va + (v_first[(size_t)bt * 512 + kidx] - va) * gv0;
        vbuf[kidx + 1] = vb2 + (v_first[(size_t)bt * 512 + kidx + 1] - vb2) * gv1;
    }
    __syncthreads();

    float rf[8];
    #pragma unroll
    for (int j = 0; j < 8; ++j) {
        int nn = off + j;
        int nn2 = (nn + 32) & 63;
        float val = rbuf[h * 64 + nn] * rscale * ln_r[nn];
        float oth = rbuf[h * 64 + nn2] * rscale * ln_r[nn2];
        float rot = (nn < 32) ? -oth : oth;
        rf[j] = val * cosb[nn] + rot * sinb[nn];
    }
    float kfv[2];
    #pragma unroll
    for (int j = 0; j < 2; ++j) {
        int nn = ko2 + j;
        int nn2 = (nn + 32) & 63;
        float val = kbuf[kvh * 64 + nn] * kscale * ln_k[nn];
        float oth = kbuf[kvh * 64 + nn2] * kscale * ln_k[nn2];
        float rot = (nn < 32) ? -oth : oth;
        float kr = val * cosb[nn] + rot * sinb[nn];
        float gk = sigmf(smrow[6656 + kvh * 64 + nn] + k0b[kvh * 64 + nn]);
        kfv[j] = kr + (k_first[(size_t)bt * 512 + kvh * 64 + nn] - kr) * gk;
    }
    __syncthreads();
    kbuf[kidx] = kfv[0]; kbuf[kidx + 1] = kfv[1];
    float kn = kfv[0] * kfv[0] + kfv[1] * kfv[1];
    kn += __shfl_xor(kn, 1); kn += __shfl_xor(kn, 2); kn += __shfl_xor(kn, 4);
    kn += __shfl_xor(kn, 8); kn += __shfl_xor(kn, 16);
    if ((tid & 31) == 0) knorms[kvh] = fmaxf(sqrtf(kn), 1e-12f);
    __syncthreads();

    const float knv = knorms[h >> 2];
    char* scb = SC + ((size_t)(b * H_ + h) * T_ + t) * 896;
    __hip_bfloat16* us = (__hip_bfloat16*)scb;
    float* df = (float*)(scb + 640);
    float4 w1a = *(const float4*)(smrow + n0);
    float4 w1b = *(const float4*)(smrow + n0 + 4);
    float4 ara = *(const float4*)(smrow + 2048 + n0);
    float4 arb = *(const float4*)(smrow + 2048 + n0 + 4);
    float4 ga  = *(const float4*)(smrow + 4608 + n0);
    float4 gb  = *(const float4*)(smrow + 4608 + n0 + 4);
    float w1arr[8] = {w1a.x, w1a.y, w1a.z, w1a.w, w1b.x, w1b.y, w1b.z, w1b.w};
    float aarr[8] = {ara.x, ara.y, ara.z, ara.w, arb.x, arb.y, arb.z, arb.w};
    float garr[8] = {ga.x, ga.y, ga.z, ga.w, gb.x, gb.y, gb.z, gb.w};
    __align__(16) __hip_bfloat16 t_r[8], t_k[8], t_a[8], t_b[8], t_v[8], t_vb[8], t_g[8];
    __align__(16) float t_d[8];
    float bsum = 0.f;
    #pragma unroll
    for (int j = 0; j < 8; ++j) {
        int nn = off + j, n = n0 + j;
        float w1 = w1arr[j] + w0[n];
        float w2v = -log1pf(expf(-w1)) - 0.5f;
        float av = sigmf(aarr[j] + a0[n]);
        float dec = expf(-expf(w2v));
        float kb = kbuf[(h >> 2) * 64 + nn];
        float vbv = vbuf[(h >> 2) * 64 + nn];
        float kkv = kb / knv;
        float ksc = kb * (1.f - w2v + av);
        t_r[j] = __float2bfloat16(rf[j]);
        t_k[j] = __float2bfloat16(ksc);
        t_a[j] = __float2bfloat16(-kkv);
        t_b[j] = __float2bfloat16(kkv * av);
        t_v[j] = __float2bfloat16(vbv);
        t_d[j] = dec;
        t_vb[j] = __float2bfloat16(vbv);
        t_g[j] = __float2bfloat16(garr[j]);
        bsum += rf[j] * ksc * r_k[h * 64 + nn];
    }
    *(uint4*)&us[off]        = *(const uint4*)t_r;
    *(uint4*)&us[64 + off]   = *(const uint4*)t_k;
    *(uint4*)&us[128 + off]  = *(const uint4*)t_a;
    *(uint4*)&us[192 + off]  = *(const uint4*)t_b;
    *(uint4*)&us[256 + off]  = *(const uint4*)t_v;
    *(float4*)&df[off]       = *(const float4*)&t_d[0];
    *(float4*)&df[off + 4]   = *(const float4*)&t_d[4];
    *(uint4*)&VB[(size_t)bt * HN_ + n0] = *(const uint4*)t_vb;
    *(uint4*)&G[(size_t)bt * HN_ + n0]  = *(const uint4*)t_g;
    bsum += __shfl_xor(bsum, 1); bsum += __shfl_xor(bsum, 2); bsum += __shfl_xor(bsum, 4);
    if ((tid & 7) == 0) SB[bt * H_ + h] = bsum;
}

// ---------------- chunked scan pass 1 (4-wave unified): wave w owns rows [16w,16w+16) of BOTH P,S ----------------
__global__ __launch_bounds__(256) void scan_pass1(
    const char* __restrict__ SC, float* __restrict__ Q, float* __restrict__ O,
    float* __restrict__ Pf, float* __restrict__ Sf) {
    const int chunk = blockIdx.x;
    const int bh = chunk >> 4, c = chunk & 15;
    const int b = bh >> 5, h = bh & 31;
    const int tid = threadIdx.x;
    const int wid = tid >> 6, lane = tid & 63;
    const int cq = lane >> 4;            // col quarter
    const int cb = cq << 4;              // col base
    const int row = (wid << 4) + (lane & 15);
    const char* base = SC + ((size_t)bh * T_ + (size_t)c * CH) * 896;
    __shared__ __align__(16) float ld[2][6][64];  // 0=a 1=b 2=d 3=k 4=r 5=v

    f32x4 P4[4], S4[4];
    #pragma unroll
    for (int j = 0; j < 4; ++j)
        #pragma unroll
        for (int e = 0; e < 4; ++e) {
            P4[j][e] = (cb + 4 * j + e == row) ? 1.f : 0.f;
            S4[j][e] = 0.f;
        }

    float p0 = 0.f, p1 = 0.f;
    auto LOADT = [&](int t) {
        const __hip_bfloat16* us = (const __hip_bfloat16*)(base + (size_t)t * 896);
        if (wid == 0)      { p0 = __bfloat162float(us[128 + lane]); p1 = __bfloat162float(us[lane]); }       // a, r
        else if (wid == 1) { p0 = __bfloat162float(us[192 + lane]); p1 = __bfloat162float(us[256 + lane]); } // b, v
        else if (wid == 2) { p0 = *(const float*)(base + (size_t)t * 896 + 640 + 4 * lane); }                // d
        else               { p0 = __bfloat162float(us[64 + lane]); }                                         // k
    };
    LOADT(0);
    float* qrow = Q + (size_t)chunk * CH * 64 + row;
    float* orow = O + ((size_t)b * T_ + (size_t)c * CH) * HN_ + h * 64 + row;
    for (int t = 0; t < CH; ++t) {
        const int buf = t & 1;
        if (wid == 0)      { ld[buf][0][lane] = p0; ld[buf][4][lane] = p1; }
        else if (wid == 1) { ld[buf][1][lane] = p0; ld[buf][5][lane] = p1; }
        else if (wid == 2) { ld[buf][2][lane] = p0; }
        else               { ld[buf][3][lane] = p0; }
        __syncthreads();
        if (t + 1 < CH) LOADT(t + 1);
        f32x4 a4[4];
        #pragma unroll
        for (int j = 0; j < 4; ++j) a4[j] = *(const f32x4*)&ld[buf][0][cb + 4 * j];
        f32x4 dpv = {0,0,0,0}, dsv = {0,0,0,0};
        #pragma unroll
        for (int j = 0; j < 4; ++j) { dpv += P4[j] * a4[j]; dsv += S4[j] * a4[j]; }
        float dp = dpv[0] + dpv[1] + dpv[2] + dpv[3];
        float dsd = dsv[0] + dsv[1] + dsv[2] + dsv[3];
        dp += __shfl_xor(dp, 16);  dp += __shfl_xor(dp, 32);
        dsd += __shfl_xor(dsd, 16); dsd += __shfl_xor(dsd, 32);
        const float vt = ld[buf][5][row];
        const f32x4 cPv = {dp, dp, dp, dp}, sav = {dsd, dsd, dsd, dsd}, vtv = {vt, vt, vt, vt};
        f32x4 qp = {0,0,0,0}, op = {0,0,0,0};
        #pragma unroll
        for (int j = 0; j < 4; ++j) {
            f32x4 d4 = *(const f32x4*)&ld[buf][2][cb + 4 * j];
            f32x4 b4 = *(const f32x4*)&ld[buf][1][cb + 4 * j];
            f32x4 k4 = *(const f32x4*)&ld[buf][3][cb + 4 * j];
            f32x4 r4 = *(const f32x4*)&ld[buf][4][cb + 4 * j];
            f32x4 Pn = P4[j] * d4 + cPv * b4;
            f32x4 Sn = S4[j] * d4 + sav * b4 + vtv * k4;
            P4[j] = Pn; S4[j] = Sn;
            qp += Pn * r4; op += Sn * r4;
        }
        float qs = qp[0] + qp[1] + qp[2] + qp[3];
        float os = op[0] + op[1] + op[2] + op[3];
        qs += __shfl_xor(qs, 16); qs += __shfl_xor(qs, 32);
        os += __shfl_xor(os, 16); os += __shfl_xor(os, 32);
        if (cq == 0) {
            qrow[(size_t)t * 64] = qs;
            orow[(size_t)t * HN_] = os;   // oloc, unscaled
        }
    }
    float* pf = Pf + (size_t)chunk * 4096 + (size_t)row * 64 + cb;
    float* sf = Sf + (size_t)chunk * 4096 + (size_t)row * 64 + cb;
    #pragma unroll
    for (int j = 0; j < 4; ++j) {
        *(f32x4*)(pf + 4 * j) = P4[j];
        *(f32x4*)(sf + 4 * j) = S4[j];
    }
}

// ---------------- pass 2: propagate chunk-initial states (Sf -> Sinit in place) ----------------
__global__ __launch_bounds__(256) void scan_pass2(
    const float* __restrict__ Pf, float* __restrict__ Sf, const float* __restrict__ state) {
    const int blk = blockIdx.x;
    const int bh = blk >> 2, rb = blk & 3;
    const int tid = threadIdx.x;
    const int lv = tid >> 4, c0 = (tid & 15) << 2;
    __shared__ __align__(16) float S[16][68];
    __shared__ __align__(16) float P[64][64];

    *(f32x4*)&S[lv][c0] = *(const f32x4*)&state[(size_t)bh * 4096 + 1024 * rb + tid * 4];
    const size_t pbase = (size_t)(bh * NCH) * 4096;
    {
        f32x4 p0[4];
        #pragma unroll
        for (int j = 0; j < 4; ++j) p0[j] = *(const f32x4*)&Pf[pbase + tid * 16 + 4 * j];
        #pragma unroll
        for (int j = 0; j < 4; ++j) *(f32x4*)(&P[0][0] + tid * 16 + 4 * j) = p0[j];
    }
    __syncthreads();

    for (int c = 0; c < NCH; ++c) {
        const size_t ck = (size_t)(bh * NCH + c) * 4096;
        f32x4 pp[4];
        if (c + 1 < NCH) {
            #pragma unroll
            for (int j = 0; j < 4; ++j) pp[j] = *(const f32x4*)&Pf[ck + 4096 + tid * 16 + 4 * j];
        }
        f32x4 acc = *(const f32x4*)&Sf[ck + 1024 * rb + tid * 4];   // S_loc(c)
        f32x4 cur = *(const f32x4*)&S[lv][c0];                      // Sinit(c)
        #pragma unroll 4
        for (int k4 = 0; k4 < 64; k4 += 4) {
            f32x4 sk4 = *(const f32x4*)&S[lv][k4];
            #pragma unroll
            for (int kk = 0; kk < 4; ++kk) {
                f32x4 pr = *(const f32x4*)&P[k4 + kk][c0];
                f32x4 sv = {sk4[kk], sk4[kk], sk4[kk], sk4[kk]};
                acc += sv * pr;
            }
        }
        __syncthreads();
        *(f32x4*)&S[lv][c0] = acc;
        if (c + 1 < NCH) {
            #pragma unroll
            for (int j = 0; j < 4; ++j) *(f32x4*)(&P[0][0] + tid * 16 + 4 * j) = pp[j];
        }
        *(f32x4*)&Sf[ck + 1024 * rb + tid * 4] = cur;
        __syncthreads();
    }
}

// ---------------- pass 3 + post fused: u = ((Sinit·q + oloc)·N^-0.5 + SB·VB)·G -> bf16 ----------------
__global__ __launch_bounds__(64) void pass3_post(
    const float* __restrict__ Q, const float* __restrict__ Sinit, const float* __restrict__ OL,
    const float* __restrict__ SB, const __hip_bfloat16* __restrict__ VB,
    const __hip_bfloat16* __restrict__ G, __hip_bfloat16* __restrict__ Ub) {
    const int chunk = blockIdx.x;
    const int bh = chunk >> 4, c = chunk & 15;
    const int b = bh >> 5, h = bh & 31;
    const int t = threadIdx.x;
    __shared__ __align__(16) float S[64][64];
    #pragma unroll
    for (int j = 0; j < 16; ++j)
        *(f32x4*)&S[t][4 * j] = *(const f32x4*)&Sinit[(size_t)chunk * 4096 + (size_t)t * 64 + 4 * j];
    __syncthreads();
    float q[64];
    #pragma unroll
    for (int j = 0; j < 16; ++j)
        *(f32x4*)&q[4 * j] = *(const f32x4*)&Q[((size_t)chunk * CH + t) * 64 + 4 * j];
    const size_t bt = (size_t)b * T_ + (size_t)c * CH + t;
    const float sb = SB[bt * H_ + h];
    const float* olrow = OL + bt * HN_ + h * 64;
    const __hip_bfloat16* vbrow = VB + bt * HN_ + h * 64;
    const __hip_bfloat16* grow = G + bt * HN_ + h * 64;
    __hip_bfloat16* urow = Ub + bt * HN_ + h * 64;
    #pragma unroll 4
    for (int v = 0; v < 64; ++v) {
        f32x4 a = {0, 0, 0, 0};
        #pragma unroll
        for (int j = 0; j < 16; ++j)
            a += *(const f32x4*)&S[v][4 * j] * *(const f32x4*)&q[4 * j];
        float o = (a[0] + a[1] + a[2] + a[3] + olrow[v]) * 0.125f;
        float u = (o + sb * __bfloat162float(vbrow[v])) * __bfloat162float(grow[v]);
        urow[v] = __float2bfloat16(u);
    }
}

extern "C" void kernel_launch(void* const* d_in, const int* in_sizes, int n_in,
                              void* d_out, int out_size, void* d_ws, size_t ws_size,
                              hipStream_t stream) {
    (void)in_sizes; (void)n_in; (void)out_size; (void)ws_size;
    const float* x_in    = (const float*)d_in[0];
    const float* v_first = (const float*)d_in[1];
    const float* k_first = (const float*)d_in[2];
    const float* state   = (const float*)d_in[3];
    const float* calc_cos= (const float*)d_in[4];
    const float* calc_sin= (const float*)d_in[5];
    const float* wavgk1  = (const float*)d_in[6];
    const float* w0      = (const float*)d_in[7];
    const float* w2      = (const float*)d_in[8];
    const float* a0      = (const float*)d_in[9];
    const float* a2      = (const float*)d_in[10];
    const float* v0      = (const float*)d_in[11];
    const float* v2      = (const float*)d_in[12];
    const float* g2      = (const float*)d_in[13];
    const float* k0      = (const float*)d_in[14];
    const float* k2      = (const float*)d_in[15];
    const float* r_k     = (const float*)d_in[16];
    const float* RKV_w   = (const float*)d_in[17];
    const float* O_w     = (const float*)d_in[18];
    const float* R_bias  = (const float*)d_in[19];
    const float* K_bias  = (const float*)d_in[20];
    const float* V_bias  = (const float*)d_in[21];
    const float* O_bias  = (const float*)d_in[22];
    const float* ln_r    = (const float*)d_in[23];
    const float* ln_k    = (const float*)d_in[24];
    const float* ln1     = (const float*)d_in[25];
    float* out = (float*)d_out;

    char* ws = (char*)d_ws;
    size_t off = 0;
    auto alloc = [&](size_t bytes) -> char* {
        char* p = ws + off;
        off = (off + bytes + 255) & ~(size_t)255;
        return p;
    };
    // ---- persistent region (~101 MB) ----
    char*  SCb = alloc((size_t)64 * T_ * 896);                        // compose -> pass1
    __hip_bfloat16* Ub = (__hip_bfloat16*)SCb;                        // aliases SCb (pass3 -> final gemm)
    __hip_bfloat16* VBb = (__hip_bfloat16*)alloc((size_t)MTOK * HN_ * 2); // compose -> pass3
    __hip_bfloat16* Gb  = (__hip_bfloat16*)alloc((size_t)MTOK * HN_ * 2); // compose -> pass3
    float* SBf = (float*)alloc((size_t)MTOK * H_ * 4);                // compose -> pass3
    float* Of  = (float*)alloc((size_t)MTOK * HN_ * 4);               // pass1 -> pass3 (oloc)
    __hip_bfloat16* OWb = (__hip_bfloat16*)alloc((size_t)2048 * 2048 * 2); // prep -> final gemm

    // ---- overlapped region: stage A (pre-scan, ~123 MB) ----
    size_t ovl = off;
    float* SMf = (float*)alloc((size_t)MTOK * SMN * 4);               // gemm3 -> compose
    __hip_bfloat16* Xb     = (__hip_bfloat16*)alloc((size_t)MTOK * HN_ * 2);
    __hip_bfloat16* RKVb   = (__hip_bfloat16*)alloc((size_t)3072 * 2048 * 2);
    __hip_bfloat16* WT1b   = (__hip_bfloat16*)alloc((size_t)320 * 2048 * 2);
    __hip_bfloat16* Wcatb  = (__hip_bfloat16*)alloc((size_t)SMN * KCAT * 2);
    __hip_bfloat16* XWmodb = (__hip_bfloat16*)alloc((size_t)MTOK * KCAT * 2);
    float* RKVf  = (float*)alloc((size_t)MTOK * 3072 * 4);
    float* XWp   = (float*)alloc((size_t)4 * MTOK * KCAT * 4);        // split-K partials
    // ---- overlapped region: stage B (scan, ~50 MB) — reuses stage A space ----
    off = ovl;
    float* Qf  = (float*)alloc((size_t)NCHUNK * CH * 64 * 4);         // pass1 -> pass3
    float* Pff = (float*)alloc((size_t)NCHUNK * 4096 * 4);            // pass1 -> pass2
    float* Sff = (float*)alloc((size_t)NCHUNK * 4096 * 4);            // pass1 -> pass3

    // merged weight prep
    {
        long total = (long)PREP_N1 + PREP_N2 + PREP_N3 + PREP_N4;
        prep_kernel<<<(int)((total + 255) / 256), 256, 0, stream>>>(
            RKV_w, O_w, wavgk1, w2, a2, v2, g2, k2, RKVb, OWb, WT1b, Wcatb);
    }

    // x = rmsnorm(x_in, ln1) -> bf16
    rmsnorm_kernel<<<MTOK, 256, 0, stream>>>(x_in, ln1, Xb);

    // big GEMMs (global_load_lds 128-tile, XCD-swizzled 1D grid)
    gemm_bt128<<<(3072 / 128) * (MTOK / 128), 256, 0, stream>>>(Xb, RKVb, RKVf, MTOK, 3072, 2048, nullptr, nullptr);
    gemm_xw_sk<<<dim3(KCAT / 64, MTOK / 64, 4), 256, 0, stream>>>(Xb, WT1b, XWp, MTOK, KCAT, 2048);
    xw_reduce<<<(MTOK * KCAT + 255) / 256, 256, 0, stream>>>(XWp, XWmodb);
    gemm_bt128<<<(SMN / 128) * (MTOK / 128), 256, 0, stream>>>(XWmodb, Wcatb, SMf, MTOK, SMN, KCAT, nullptr, nullptr);

    // compose scan records (+ G gate, VB, SB)
    compose_kernel<<<MTOK, 256, 0, stream>>>(RKVf, SMf, v_first, k_first, calc_cos, calc_sin,
                                             R_bias, K_bias, V_bias, w0, a0, v0, k0,
                                             ln_r, ln_k, r_k, SCb, VBb, SBf, Gb);

    // chunked RWKV scan: pass1 -> pass2 (chunk-sequential) -> pass3+post
    scan_pass1<<<NCHUNK, 256, 0, stream>>>(SCb, Qf, Of, Pff, Sff);
    scan_pass2<<<B_ * H_ * 4, 256, 0, stream>>>(Pff, Sff, state);
    pass3_post<<<NCHUNK, 64, 0, stream>>>(Qf, Sff, Of, SBf, VBb, Gb, Ub);

    // output GEMM (adds x_in and O_bias in epilogue)
    gemm_bt128<<<(HN_ / 128) * (MTOK / 128), 256, 0, stream>>>(Ub, OWb, out, MTOK, HN_, 2048, O_bias, x_in);
}

// Round 14
// 392.435 us; speedup vs baseline: 1.0721x; 1.0520x over previous
//
#include <hip/hip_runtime.h>
#include <hip/hip_bf16.h>
#include <stdint.h>

// Problem constants
#define B_ 2
#define T_ 1024
#define H_ 32
#define N_ 64
#define HN_ 2048
#define KVH_ 8
#define KVD_ 512
#define MTOK 2048        // B*T
#define SMN 7168         // concat small-gemm output width
#define KCAT 320
#define CH 64            // scan chunk length
#define NCH 16           // T/CH
#define NCHUNK 1024      // B*H*NCH

typedef __bf16 bf16x8 __attribute__((ext_vector_type(8)));
typedef float f32x4 __attribute__((ext_vector_type(4)));

typedef __attribute__((address_space(1))) uint32_t gu32;
typedef __attribute__((address_space(3))) uint32_t lu32;
__device__ __forceinline__ void gload16(const void* g, void* l) {
    __builtin_amdgcn_global_load_lds((gu32*)g, (lu32*)l, 16, 0, 0);
}

__device__ __forceinline__ float sigmf(float x) { return 1.f / (1.f + expf(-x)); }

// ---------------- merged prep kernel (4 elems/thread, 8B bf16 stores) ----------------
#define PREP_N1 (3072 * 2048)
#define PREP_N2 (2048 * 2048)
#define PREP_N3 (320 * 2048)
#define PREP_N4 (SMN * KCAT)
__global__ void prep_kernel(const float* __restrict__ RKV_w, const float* __restrict__ O_w,
                            const float* __restrict__ wavgk1,
                            const float* __restrict__ w2, const float* __restrict__ a2,
                            const float* __restrict__ v2, const float* __restrict__ g2,
                            const float* __restrict__ k2,
                            __hip_bfloat16* __restrict__ RKVb, __hip_bfloat16* __restrict__ OWb,
                            __hip_bfloat16* __restrict__ WT1b, __hip_bfloat16* __restrict__ Wcatb) {
    long i = ((long)blockIdx.x * 256 + threadIdx.x) * 4;
    __align__(8) __hip_bfloat16 t[4];
    if (i < PREP_N1) {
        float4 v = *(const float4*)&RKV_w[i];
        t[0] = __float2bfloat16(v.x); t[1] = __float2bfloat16(v.y);
        t[2] = __float2bfloat16(v.z); t[3] = __float2bfloat16(v.w);
        *(uint2*)&RKVb[i] = *(const uint2*)t;
        return;
    }
    i -= PREP_N1;
    if (i < PREP_N2) {
        float4 v = *(const float4*)&O_w[i];
        t[0] = __float2bfloat16(v.x); t[1] = __float2bfloat16(v.y);
        t[2] = __float2bfloat16(v.z); t[3] = __float2bfloat16(v.w);
        *(uint2*)&OWb[i] = *(const uint2*)t;
        return;
    }
    i -= PREP_N2;
    if (i < PREP_N3) {
        int c = (int)(i / 2048), r = (int)(i % 2048);   // 4 consecutive i share c (2048%4==0)
        #pragma unroll
        for (int j = 0; j < 4; ++j)
            t[j] = __float2bfloat16(wavgk1[(size_t)(r + j) * KCAT + c]);
        *(uint2*)&WT1b[i] = *(const uint2*)t;
        return;
    }
    i -= PREP_N3;
    if (i >= PREP_N4) return;
    int j = (int)(i / KCAT), k = (int)(i % KCAT);       // 4 consecutive share j (320%4==0)
    #pragma unroll
    for (int e = 0; e < 4; ++e) {
        int kk = k + e;
        float v = 0.f;
        if (j < 2048)      { if (kk < 64)              v = w2[(size_t)kk * 2048 + j]; }
        else if (j < 4096) { if (kk >= 64 && kk < 128)  v = a2[(size_t)(kk - 64) * 2048 + (j - 2048)]; }
        else if (j < 4608) { if (kk >= 128 && kk < 160) v = v2[(size_t)(kk - 128) * 512 + (j - 4096)]; }
        else if (j < 6656) { if (kk >= 160 && kk < 288) v = g2[(size_t)(kk - 160) * 2048 + (j - 4608)]; }
        else               { if (kk >= 288)             v = k2[(size_t)(kk - 288) * 512 + (j - 6656)]; }
        t[e] = __float2bfloat16(v);
    }
    *(uint2*)&Wcatb[i] = *(const uint2*)t;
}

// ---------------- RMSNorm over HN per token -> bf16 ----------------
__global__ __launch_bounds__(256) void rmsnorm_kernel(const float* __restrict__ x,
                                                      const float* __restrict__ ln1,
                                                      __hip_bfloat16* __restrict__ out) {
    const int bt = blockIdx.x, tid = threadIdx.x;
    const float* row = x + (size_t)bt * HN_;
    float4 v0 = *(const float4*)(row + tid * 8);
    float4 v1 = *(const float4*)(row + tid * 8 + 4);
    float s = v0.x*v0.x + v0.y*v0.y + v0.z*v0.z + v0.w*v0.w
            + v1.x*v1.x + v1.y*v1.y + v1.z*v1.z + v1.w*v1.w;
    for (int m = 1; m < 64; m <<= 1) s += __shfl_xor(s, m);
    __shared__ float red[4];
    if ((tid & 63) == 0) red[tid >> 6] = s;
    __syncthreads();
    s = red[0] + red[1] + red[2] + red[3];
    float scale = rsqrtf(s * (1.f / HN_) + 1e-6f);
    float vals[8] = {v0.x, v0.y, v0.z, v0.w, v1.x, v1.y, v1.z, v1.w};
    __align__(16) __hip_bfloat16 tmp[8];
    #pragma unroll
    for (int j = 0; j < 8; ++j)
        tmp[j] = __float2bfloat16(vals[j] * scale * ln1[tid * 8 + j]);
    *(uint4*)&out[(size_t)bt * HN_ + tid * 8] = *(const uint4*)tmp;
}

// ---------------- split-K 64-tile GEMM for XW (N=320): partial f32 out ----------------
__global__ __launch_bounds__(256) void gemm_xw_sk(const __hip_bfloat16* __restrict__ A,
                                                  const __hip_bfloat16* __restrict__ B,
                                                  float* __restrict__ Cp, int M, int N, int K) {
    __shared__ __align__(16) __hip_bfloat16 As[64][40];
    __shared__ __align__(16) __hip_bfloat16 Bs[64][40];
    const int tid = threadIdx.x;
    const int wave = tid >> 6, lane = tid & 63;
    const int wr = (wave >> 1) * 32, wc = (wave & 1) * 32;
    const int brow = blockIdx.y << 6, bcol = blockIdx.x << 6;
    const int z = blockIdx.z;
    const int kbeg = z * (K >> 2), kend = kbeg + (K >> 2);
    const int lrow = tid >> 2, lcol = (tid & 3) << 3;
    const int fr = lane & 15, ko = (lane >> 4) << 3;
    f32x4 acc[2][2] = {};
    for (int k0 = kbeg; k0 < kend; k0 += 32) {
        uint4 av = *(const uint4*)(A + (size_t)(brow + lrow) * K + k0 + lcol);
        uint4 bv = *(const uint4*)(B + (size_t)(bcol + lrow) * K + k0 + lcol);
        *(uint4*)(&As[lrow][lcol]) = av;
        *(uint4*)(&Bs[lrow][lcol]) = bv;
        __syncthreads();
        bf16x8 af0 = *(const bf16x8*)(&As[wr + fr][ko]);
        bf16x8 af1 = *(const bf16x8*)(&As[wr + 16 + fr][ko]);
        bf16x8 bf0 = *(const bf16x8*)(&Bs[wc + fr][ko]);
        bf16x8 bf1 = *(const bf16x8*)(&Bs[wc + 16 + fr][ko]);
        acc[0][0] = __builtin_amdgcn_mfma_f32_16x16x32_bf16(af0, bf0, acc[0][0], 0, 0, 0);
        acc[0][1] = __builtin_amdgcn_mfma_f32_16x16x32_bf16(af0, bf1, acc[0][1], 0, 0, 0);
        acc[1][0] = __builtin_amdgcn_mfma_f32_16x16x32_bf16(af1, bf0, acc[1][0], 0, 0, 0);
        acc[1][1] = __builtin_amdgcn_mfma_f32_16x16x32_bf16(af1, bf1, acc[1][1], 0, 0, 0);
        __syncthreads();
    }
    const int cr = (lane >> 4) << 2, cc = lane & 15;
    float* Cz = Cp + (size_t)z * M * N;
    #pragma unroll
    for (int i = 0; i < 2; ++i)
        #pragma unroll
        for (int j = 0; j < 2; ++j)
            #pragma unroll
            for (int r = 0; r < 4; ++r) {
                int row = brow + wr + i * 16 + cr + r;
                int col = bcol + wc + j * 16 + cc;
                Cz[(size_t)row * N + col] = acc[i][j][r];
            }
}

// ---------------- reduce split-K partials + xw activation -> bf16 ----------------
__global__ void xw_reduce(const float* __restrict__ Cp, __hip_bfloat16* __restrict__ out) {
    long i = (long)blockIdx.x * 256 + threadIdx.x;
    if (i >= (long)MTOK * KCAT) return;
    const long MN = (long)MTOK * KCAT;
    float v = Cp[i] + Cp[i + MN] + Cp[i + 2 * MN] + Cp[i + 3 * MN];
    int c = (int)(i % KCAT);
    if (c < 64) v = tanhf(v);
    else if (c >= 160 && c < 288) v = sigmf(v);
    out[i] = __float2bfloat16(v);
}

// ---------------- 128-tile MFMA GEMM, global_load_lds staging + XCD swizzle ----------------
__global__ __launch_bounds__(256) void gemm_bt128(const __hip_bfloat16* __restrict__ A,
                                                  const __hip_bfloat16* __restrict__ B,
                                                  float* __restrict__ C, int M, int N, int K,
                                                  const float* __restrict__ bias,
                                                  const float* __restrict__ addend) {
    __shared__ __align__(16) __hip_bfloat16 As[128][32];
    __shared__ __align__(16) __hip_bfloat16 Bs[128][32];
    const int nwg = gridDim.x;
    int wg = blockIdx.x;
    wg = (wg & 7) * (nwg >> 3) + (wg >> 3);     // XCD swizzle (bijective: nwg%8==0)
    const int nx = N >> 7;
    const int bx = wg % nx, by = wg / nx;
    const int brow = by << 7, bcol = bx << 7;
    const int tid = threadIdx.x;
    const int wave = tid >> 6, lane = tid & 63;
    const int wr = (wave >> 1) * 64, wc = (wave & 1) * 64;
    const int fr = lane & 15, ko = (lane >> 4) << 3;
    const int ar0 = wave * 32;
    const int sr = lane >> 2;
    const int sc = (lane & 3) << 3;
    f32x4 acc[4][4] = {};
    const __hip_bfloat16* gA0 = A + (size_t)(brow + ar0 + sr) * K + sc;
    const __hip_bfloat16* gA1 = A + (size_t)(brow + ar0 + 16 + sr) * K + sc;
    const __hip_bfloat16* gB0 = B + (size_t)(bcol + ar0 + sr) * K + sc;
    const __hip_bfloat16* gB1 = B + (size_t)(bcol + ar0 + 16 + sr) * K + sc;
    for (int k0 = 0; k0 < K; k0 += 32) {
        gload16(gA0 + k0, &As[ar0][0]);
        gload16(gA1 + k0, &As[ar0 + 16][0]);
        gload16(gB0 + k0, &Bs[ar0][0]);
        gload16(gB1 + k0, &Bs[ar0 + 16][0]);
        __syncthreads();
        bf16x8 af[4], bfr[4];
        #pragma unroll
        for (int i = 0; i < 4; ++i) {
            af[i]  = *(const bf16x8*)(&As[wr + i * 16 + fr][ko]);
            bfr[i] = *(const bf16x8*)(&Bs[wc + i * 16 + fr][ko]);
        }
        #pragma unroll
        for (int i = 0; i < 4; ++i)
            #pragma unroll
            for (int j = 0; j < 4; ++j)
                acc[i][j] = __builtin_amdgcn_mfma_f32_16x16x32_bf16(af[i], bfr[j], acc[i][j], 0, 0, 0);
        __syncthreads();
    }
    const int cr = (lane >> 4) << 2, cc = lane & 15;
    #pragma unroll
    for (int i = 0; i < 4; ++i)
        #pragma unroll
        for (int j = 0; j < 4; ++j) {
            const int row0 = brow + wr + i * 16 + cr;
            const int col = bcol + wc + j * 16 + cc;
            #pragma unroll
            for (int r = 0; r < 4; ++r) {
                float v = acc[i][j][r];
                if (bias) v += bias[col];
                if (addend) v += addend[(size_t)(row0 + r) * N + col];
                C[(size_t)(row0 + r) * N + col] = v;
            }
        }
}

// ---------------- segment-aware 128-tile GEMM for SMf (block-diagonal Wcat) ----------------
// Output col-tile determines its true K-range (boundaries %128 cols, %32 K).
__global__ __launch_bounds__(256) void gemm_bt128_seg(const __hip_bfloat16* __restrict__ A,
                                                      const __hip_bfloat16* __restrict__ B,
                                                      float* __restrict__ C) {
    const int M = MTOK, N = SMN, K = KCAT;
    __shared__ __align__(16) __hip_bfloat16 As[128][32];
    __shared__ __align__(16) __hip_bfloat16 Bs[128][32];
    const int nwg = gridDim.x;
    int wg = blockIdx.x;
    wg = (wg & 7) * (nwg >> 3) + (wg >> 3);
    const int nx = N >> 7;
    const int bx = wg % nx, by = wg / nx;
    const int brow = by << 7, bcol = bx << 7;
    int kbeg, kend;
    if (bcol < 2048)      { kbeg = 0;   kend = 64;  }
    else if (bcol < 4096) { kbeg = 64;  kend = 128; }
    else if (bcol < 4608) { kbeg = 128; kend = 160; }
    else if (bcol < 6656) { kbeg = 160; kend = 288; }
    else                  { kbeg = 288; kend = 320; }
    const int tid = threadIdx.x;
    const int wave = tid >> 6, lane = tid & 63;
    const int wr = (wave >> 1) * 64, wc = (wave & 1) * 64;
    const int fr = lane & 15, ko = (lane >> 4) << 3;
    const int ar0 = wave * 32;
    const int sr = lane >> 2;
    const int sc = (lane & 3) << 3;
    f32x4 acc[4][4] = {};
    const __hip_bfloat16* gA0 = A + (size_t)(brow + ar0 + sr) * K + sc;
    const __hip_bfloat16* gA1 = A + (size_t)(brow + ar0 + 16 + sr) * K + sc;
    const __hip_bfloat16* gB0 = B + (size_t)(bcol + ar0 + sr) * K + sc;
    const __hip_bfloat16* gB1 = B + (size_t)(bcol + ar0 + 16 + sr) * K + sc;
    for (int k0 = kbeg; k0 < kend; k0 += 32) {
        gload16(gA0 + k0, &As[ar0][0]);
        gload16(gA1 + k0, &As[ar0 + 16][0]);
        gload16(gB0 + k0, &Bs[ar0][0]);
        gload16(gB1 + k0, &Bs[ar0 + 16][0]);
        __syncthreads();
        bf16x8 af[4], bfr[4];
        #pragma unroll
        for (int i = 0; i < 4; ++i) {
            af[i]  = *(const bf16x8*)(&As[wr + i * 16 + fr][ko]);
            bfr[i] = *(const bf16x8*)(&Bs[wc + i * 16 + fr][ko]);
        }
        #pragma unroll
        for (int i = 0; i < 4; ++i)
            #pragma unroll
            for (int j = 0; j < 4; ++j)
                acc[i][j] = __builtin_amdgcn_mfma_f32_16x16x32_bf16(af[i], bfr[j], acc[i][j], 0, 0, 0);
        __syncthreads();
    }
    const int cr = (lane >> 4) << 2, cc = lane & 15;
    #pragma unroll
    for (int i = 0; i < 4; ++i)
        #pragma unroll
        for (int j = 0; j < 4; ++j) {
            const int row0 = brow + wr + i * 16 + cr;
            const int col = bcol + wc + j * 16 + cc;
            #pragma unroll
            for (int r = 0; r < 4; ++r)
                C[(size_t)(row0 + r) * N + col] = acc[i][j][r];
        }
}

// ---------------- compose: per-token head math -> packed scan records + VB/G/SB ----------------
__global__ __launch_bounds__(256) void compose_kernel(
    const float* __restrict__ RKV, const float* __restrict__ SM,
    const float* __restrict__ v_first, const float* __restrict__ k_first,
    const float* __restrict__ cosd, const float* __restrict__ sind,
    const float* __restrict__ R_bias, const float* __restrict__ K_bias,
    const float* __restrict__ V_bias, const float* __restrict__ w0,
    const float* __restrict__ a0, const float* __restrict__ v0b,
    const float* __restrict__ k0b, const float* __restrict__ ln_r,
    const float* __restrict__ ln_k, const float* __restrict__ r_k,
    char* __restrict__ SC, __hip_bfloat16* __restrict__ VB, float* __restrict__ SB,
    __hip_bfloat16* __restrict__ G) {
    __shared__ __align__(16) float rbuf[HN_];
    __shared__ __align__(16) float kbuf[KVD_];
    __shared__ __align__(16) float vbuf[KVD_];
    __shared__ float knorms[KVH_];
    __shared__ float cosb[64], sinb[64];
    const int bt = blockIdx.x;
    const int b = bt >> 10, t = bt & 1023;
    const int tid = threadIdx.x;
    const float* rkvrow = RKV + (size_t)bt * 3072;
    const float* smrow = SM + (size_t)bt * SMN;

    if (tid < 64) {
        cosb[tid] = cosd[(size_t)bt * 64 + tid];
        sinb[tid] = sind[(size_t)bt * 64 + tid];
    }

    const int h = tid >> 3;
    const int off = (tid & 7) << 3;
    const int n0 = tid << 3;
    float rraw[8];
    {
        float4 x0 = *(const float4*)(rkvrow + n0);
        float4 x1 = *(const float4*)(rkvrow + n0 + 4);
        float4 b0 = *(const float4*)(R_bias + n0);
        float4 b1 = *(const float4*)(R_bias + n0 + 4);
        rraw[0] = x0.x + b0.x; rraw[1] = x0.y + b0.y; rraw[2] = x0.z + b0.z; rraw[3] = x0.w + b0.w;
        rraw[4] = x1.x + b1.x; rraw[5] = x1.y + b1.y; rraw[6] = x1.z + b1.z; rraw[7] = x1.w + b1.w;
    }
    float rss = 0.f;
    #pragma unroll
    for (int j = 0; j < 8; ++j) { rss += rraw[j] * rraw[j]; rbuf[n0 + j] = rraw[j]; }
    rss += __shfl_xor(rss, 1); rss += __shfl_xor(rss, 2); rss += __shfl_xor(rss, 4);
    float rscale = rsqrtf(rss * (1.f / 64.f) + 1e-6f);

    const int kvh = tid >> 5;
    const int ko2 = (tid & 31) << 1;
    const int kidx = kvh * 64 + ko2;
    float kraw0 = rkvrow[2048 + kidx] + K_bias[kidx];
    float kraw1 = rkvrow[2048 + kidx + 1] + K_bias[kidx + 1];
    float kss = kraw0 * kraw0 + kraw1 * kraw1;
    kss += __shfl_xor(kss, 1); kss += __shfl_xor(kss, 2); kss += __shfl_xor(kss, 4);
    kss += __shfl_xor(kss, 8); kss += __shfl_xor(kss, 16);
    float kscale = rsqrtf(kss * (1.f / 64.f) + 1e-6f);
    kbuf[kidx] = kraw0; kbuf[kidx + 1] = kraw1;

    {
        float va = rkvrow[2560 + kidx] + V_bias[kidx];
        float vb2 = rkvrow[2560 + kidx + 1] + V_bias[kidx + 1];
        float gv0 = sigmf(smrow[4096 + kidx] + v0b[kidx]);
        float gv1 = sigmf(smrow[4096 + kidx + 1] + v0b[kidx + 1]);
        vbuf[kidx] = va + (v_first[(size_t)bt * 512 + kidx] - va) * gv0;
        vbuf[kidx + 1] = vb2 + (v_first[(size_t)bt * 512 + kidx + 1] - vb2) * gv1;
    }
    __syncthreads();

    float rf[8];
    #pragma unroll
    for (int j = 0; j < 8; ++j) {
        int nn = off + j;
        int nn2 = (nn + 32) & 63;
        float val = rbuf[h * 64 + nn] * rscale * ln_r[nn];
        float oth = rbuf[h * 64 + nn2] * rscale * ln_r[nn2];
        float rot = (nn < 32) ? -oth : oth;
        rf[j] = val * cosb[nn] + rot * sinb[nn];
    }
    float kfv[2];
    #pragma unroll
    for (int j = 0; j < 2; ++j) {
        int nn = ko2 + j;
        int nn2 = (nn + 32) & 63;
        float val = kbuf[kvh * 64 + nn] * kscale * ln_k[nn];
        float oth = kbuf[kvh * 64 + nn2] * kscale * ln_k[nn2];
        float rot = (nn < 32) ? -oth : oth;
        float kr = val * cosb[nn] + rot * sinb[nn];
        float gk = sigmf(smrow[6656 + kvh * 64 + nn] + k0b[kvh * 64 + nn]);
        kfv[j] = kr + (k_first[(size_t)bt * 512 + kvh * 64 + nn] - kr) * gk;
    }
    __syncthreads();
    kbuf[kidx] = kfv[0]; kbuf[kidx + 1] = kfv[1];
    float kn = kfv[0] * kfv[0] + kfv[1] * kfv[1];
    kn += __shfl_xor(kn, 1); kn += __shfl_xor(kn, 2); kn += __shfl_xor(kn, 4);
    kn += __shfl_xor(kn, 8); kn += __shfl_xor(kn, 16);
    if ((tid & 31) == 0) knorms[kvh] = fmaxf(sqrtf(kn), 1e-12f);
    __syncthreads();

    const float knv = knorms[h >> 2];
    char* scb = SC + ((size_t)(b * H_ + h) * T_ + t) * 896;
    __hip_bfloat16* us = (__hip_bfloat16*)scb;
    float* df = (float*)(scb + 640);
    float4 w1a = *(const float4*)(smrow + n0);
    float4 w1b = *(const float4*)(smrow + n0 + 4);
    float4 ara = *(const float4*)(smrow + 2048 + n0);
    float4 arb = *(const float4*)(smrow + 2048 + n0 + 4);
    float4 ga  = *(const float4*)(smrow + 4608 + n0);
    float4 gb  = *(const float4*)(smrow + 4608 + n0 + 4);
    float w1arr[8] = {w1a.x, w1a.y, w1a.z, w1a.w, w1b.x, w1b.y, w1b.z, w1b.w};
    float aarr[8] = {ara.x, ara.y, ara.z, ara.w, arb.x, arb.y, arb.z, arb.w};
    float garr[8] = {ga.x, ga.y, ga.z, ga.w, gb.x, gb.y, gb.z, gb.w};
    __align__(16) __hip_bfloat16 t_r[8], t_k[8], t_a[8], t_b[8], t_v[8], t_vb[8], t_g[8];
    __align__(16) float t_d[8];
    float bsum = 0.f;
    #pragma unroll
    for (int j = 0; j < 8; ++j) {
        int nn = off + j, n = n0 + j;
        float w1 = w1arr[j] + w0[n];
        float w2v = -log1pf(expf(-w1)) - 0.5f;
        float av = sigmf(aarr[j] + a0[n]);
        float dec = expf(-expf(w2v));
        float kb = kbuf[(h >> 2) * 64 + nn];
        float vbv = vbuf[(h >> 2) * 64 + nn];
        float kkv = kb / knv;
        float ksc = kb * (1.f - w2v + av);
        t_r[j] = __float2bfloat16(rf[j]);
        t_k[j] = __float2bfloat16(ksc);
        t_a[j] = __float2bfloat16(-kkv);
        t_b[j] = __float2bfloat16(kkv * av);
        t_v[j] = __float2bfloat16(vbv);
        t_d[j] = dec;
        t_vb[j] = __float2bfloat16(vbv);
        t_g[j] = __float2bfloat16(garr[j]);
        bsum += rf[j] * ksc * r_k[h * 64 + nn];
    }
    *(uint4*)&us[off]        = *(const uint4*)t_r;
    *(uint4*)&us[64 + off]   = *(const uint4*)t_k;
    *(uint4*)&us[128 + off]  = *(const uint4*)t_a;
    *(uint4*)&us[192 + off]  = *(const uint4*)t_b;
    *(uint4*)&us[256 + off]  = *(const uint4*)t_v;
    *(float4*)&df[off]       = *(const float4*)&t_d[0];
    *(float4*)&df[off + 4]   = *(const float4*)&t_d[4];
    *(uint4*)&VB[(size_t)bt * HN_ + n0] = *(const uint4*)t_vb;
    *(uint4*)&G[(size_t)bt * HN_ + n0]  = *(const uint4*)t_g;
    bsum += __shfl_xor(bsum, 1); bsum += __shfl_xor(bsum, 2); bsum += __shfl_xor(bsum, 4);
    if ((tid & 7) == 0) SB[bt * H_ + h] = bsum;
}

// ---------------- chunked scan pass 1 (4-wave unified): wave w owns rows [16w,16w+16) of BOTH P,S ----------------
__global__ __launch_bounds__(256) void scan_pass1(
    const char* __restrict__ SC, float* __restrict__ Q, float* __restrict__ O,
    float* __restrict__ Pf, float* __restrict__ Sf) {
    const int chunk = blockIdx.x;
    const int bh = chunk >> 4, c = chunk & 15;
    const int b = bh >> 5, h = bh & 31;
    const int tid = threadIdx.x;
    const int wid = tid >> 6, lane = tid & 63;
    const int cq = lane >> 4;            // col quarter
    const int cb = cq << 4;              // col base
    const int row = (wid << 4) + (lane & 15);
    const char* base = SC + ((size_t)bh * T_ + (size_t)c * CH) * 896;
    __shared__ __align__(16) float ld[2][6][64];  // 0=a 1=b 2=d 3=k 4=r 5=v

    f32x4 P4[4], S4[4];
    #pragma unroll
    for (int j = 0; j < 4; ++j)
        #pragma unroll
        for (int e = 0; e < 4; ++e) {
            P4[j][e] = (cb + 4 * j + e == row) ? 1.f : 0.f;
            S4[j][e] = 0.f;
        }

    float p0 = 0.f, p1 = 0.f;
    auto LOADT = [&](int t) {
        const __hip_bfloat16* us = (const __hip_bfloat16*)(base + (size_t)t * 896);
        if (wid == 0)      { p0 = __bfloat162float(us[128 + lane]); p1 = __bfloat162float(us[lane]); }       // a, r
        else if (wid == 1) { p0 = __bfloat162float(us[192 + lane]); p1 = __bfloat162float(us[256 + lane]); } // b, v
        else if (wid == 2) { p0 = *(const float*)(base + (size_t)t * 896 + 640 + 4 * lane); }                // d
        else               { p0 = __bfloat162float(us[64 + lane]); }                                         // k
    };
    LOADT(0);
    float* qrow = Q + (size_t)chunk * CH * 64 + row;
    float* orow = O + ((size_t)b * T_ + (size_t)c * CH) * HN_ + h * 64 + row;
    for (int t = 0; t < CH; ++t) {
        const int buf = t & 1;
        if (wid == 0)      { ld[buf][0][lane] = p0; ld[buf][4][lane] = p1; }
        else if (wid == 1) { ld[buf][1][lane] = p0; ld[buf][5][lane] = p1; }
        else if (wid == 2) { ld[buf][2][lane] = p0; }
        else               { ld[buf][3][lane] = p0; }
        __syncthreads();
        if (t + 1 < CH) LOADT(t + 1);
        f32x4 a4[4];
        #pragma unroll
        for (int j = 0; j < 4; ++j) a4[j] = *(const f32x4*)&ld[buf][0][cb + 4 * j];
        f32x4 dpv = {0,0,0,0}, dsv = {0,0,0,0};
        #pragma unroll
        for (int j = 0; j < 4; ++j) { dpv += P4[j] * a4[j]; dsv += S4[j] * a4[j]; }
        float dp = dpv[0] + dpv[1] + dpv[2] + dpv[3];
        float dsd = dsv[0] + dsv[1] + dsv[2] + dsv[3];
        dp += __shfl_xor(dp, 16);  dp += __shfl_xor(dp, 32);
        dsd += __shfl_xor(dsd, 16); dsd += __shfl_xor(dsd, 32);
        const float vt = ld[buf][5][row];
        const f32x4 cPv = {dp, dp, dp, dp}, sav = {dsd, dsd, dsd, dsd}, vtv = {vt, vt, vt, vt};
        f32x4 qp = {0,0,0,0}, op = {0,0,0,0};
        #pragma unroll
        for (int j = 0; j < 4; ++j) {
            f32x4 d4 = *(const f32x4*)&ld[buf][2][cb + 4 * j];
            f32x4 b4 = *(const f32x4*)&ld[buf][1][cb + 4 * j];
            f32x4 k4 = *(const f32x4*)&ld[buf][3][cb + 4 * j];
            f32x4 r4 = *(const f32x4*)&ld[buf][4][cb + 4 * j];
            f32x4 Pn = P4[j] * d4 + cPv * b4;
            f32x4 Sn = S4[j] * d4 + sav * b4 + vtv * k4;
            P4[j] = Pn; S4[j] = Sn;
            qp += Pn * r4; op += Sn * r4;
        }
        float qs = qp[0] + qp[1] + qp[2] + qp[3];
        float os = op[0] + op[1] + op[2] + op[3];
        qs += __shfl_xor(qs, 16); qs += __shfl_xor(qs, 32);
        os += __shfl_xor(os, 16); os += __shfl_xor(os, 32);
        if (cq == 0) {
            qrow[(size_t)t * 64] = qs;
            orow[(size_t)t * HN_] = os;   // oloc, unscaled
        }
    }
    float* pf = Pf + (size_t)chunk * 4096 + (size_t)row * 64 + cb;
    float* sf = Sf + (size_t)chunk * 4096 + (size_t)row * 64 + cb;
    #pragma unroll
    for (int j = 0; j < 4; ++j) {
        *(f32x4*)(pf + 4 * j) = P4[j];
        *(f32x4*)(sf + 4 * j) = S4[j];
    }
}

// ---------------- pass 2: propagate chunk-initial states (Sf -> Sinit in place) ----------------
__global__ __launch_bounds__(256) void scan_pass2(
    const float* __restrict__ Pf, float* __restrict__ Sf, const float* __restrict__ state) {
    const int blk = blockIdx.x;
    const int bh = blk >> 2, rb = blk & 3;
    const int tid = threadIdx.x;
    const int lv = tid >> 4, c0 = (tid & 15) << 2;
    __shared__ __align__(16) float S[16][68];
    __shared__ __align__(16) float P[64][64];

    *(f32x4*)&S[lv][c0] = *(const f32x4*)&state[(size_t)bh * 4096 + 1024 * rb + tid * 4];
    const size_t pbase = (size_t)(bh * NCH) * 4096;
    {
        f32x4 p0[4];
        #pragma unroll
        for (int j = 0; j < 4; ++j) p0[j] = *(const f32x4*)&Pf[pbase + tid * 16 + 4 * j];
        #pragma unroll
        for (int j = 0; j < 4; ++j) *(f32x4*)(&P[0][0] + tid * 16 + 4 * j) = p0[j];
    }
    __syncthreads();

    for (int c = 0; c < NCH; ++c) {
        const size_t ck = (size_t)(bh * NCH + c) * 4096;
        f32x4 pp[4];
        if (c + 1 < NCH) {
            #pragma unroll
            for (int j = 0; j < 4; ++j) pp[j] = *(const f32x4*)&Pf[ck + 4096 + tid * 16 + 4 * j];
        }
        f32x4 acc = *(const f32x4*)&Sf[ck + 1024 * rb + tid * 4];   // S_loc(c)
        f32x4 cur = *(const f32x4*)&S[lv][c0];                      // Sinit(c)
        #pragma unroll 4
        for (int k4 = 0; k4 < 64; k4 += 4) {
            f32x4 sk4 = *(const f32x4*)&S[lv][k4];
            #pragma unroll
            for (int kk = 0; kk < 4; ++kk) {
                f32x4 pr = *(const f32x4*)&P[k4 + kk][c0];
                f32x4 sv = {sk4[kk], sk4[kk], sk4[kk], sk4[kk]};
                acc += sv * pr;
            }
        }
        __syncthreads();
        *(f32x4*)&S[lv][c0] = acc;
        if (c + 1 < NCH) {
            #pragma unroll
            for (int j = 0; j < 4; ++j) *(f32x4*)(&P[0][0] + tid * 16 + 4 * j) = pp[j];
        }
        *(f32x4*)&Sf[ck + 1024 * rb + tid * 4] = cur;
        __syncthreads();
    }
}

// ---------------- pass 3 + post fused: u = ((Sinit·q + oloc)·N^-0.5 + SB·VB)·G -> bf16 ----------------
__global__ __launch_bounds__(64) void pass3_post(
    const float* __restrict__ Q, const float* __restrict__ Sinit, const float* __restrict__ OL,
    const float* __restrict__ SB, const __hip_bfloat16* __restrict__ VB,
    const __hip_bfloat16* __restrict__ G, __hip_bfloat16* __restrict__ Ub) {
    const int chunk = blockIdx.x;
    const int bh = chunk >> 4, c = chunk & 15;
    const int b = bh >> 5, h = bh & 31;
    const int t = threadIdx.x;
    __shared__ __align__(16) float S[64][64];
    #pragma unroll
    for (int j = 0; j < 16; ++j)
        *(f32x4*)&S[t][4 * j] = *(const f32x4*)&Sinit[(size_t)chunk * 4096 + (size_t)t * 64 + 4 * j];
    __syncthreads();
    float q[64];
    #pragma unroll
    for (int j = 0; j < 16; ++j)
        *(f32x4*)&q[4 * j] = *(const f32x4*)&Q[((size_t)chunk * CH + t) * 64 + 4 * j];
    const size_t bt = (size_t)b * T_ + (size_t)c * CH + t;
    const float sb = SB[bt * H_ + h];
    const float* olrow = OL + bt * HN_ + h * 64;
    const __hip_bfloat16* vbrow = VB + bt * HN_ + h * 64;
    const __hip_bfloat16* grow = G + bt * HN_ + h * 64;
    __hip_bfloat16* urow = Ub + bt * HN_ + h * 64;
    #pragma unroll 4
    for (int v = 0; v < 64; ++v) {
        f32x4 a = {0, 0, 0, 0};
        #pragma unroll
        for (int j = 0; j < 16; ++j)
            a += *(const f32x4*)&S[v][4 * j] * *(const f32x4*)&q[4 * j];
        float o = (a[0] + a[1] + a[2] + a[3] + olrow[v]) * 0.125f;
        float u = (o + sb * __bfloat162float(vbrow[v])) * __bfloat162float(grow[v]);
        urow[v] = __float2bfloat16(u);
    }
}

extern "C" void kernel_launch(void* const* d_in, const int* in_sizes, int n_in,
                              void* d_out, int out_size, void* d_ws, size_t ws_size,
                              hipStream_t stream) {
    (void)in_sizes; (void)n_in; (void)out_size; (void)ws_size;
    const float* x_in    = (const float*)d_in[0];
    const float* v_first = (const float*)d_in[1];
    const float* k_first = (const float*)d_in[2];
    const float* state   = (const float*)d_in[3];
    const float* calc_cos= (const float*)d_in[4];
    const float* calc_sin= (const float*)d_in[5];
    const float* wavgk1  = (const float*)d_in[6];
    const float* w0      = (const float*)d_in[7];
    const float* w2      = (const float*)d_in[8];
    const float* a0      = (const float*)d_in[9];
    const float* a2      = (const float*)d_in[10];
    const float* v0      = (const float*)d_in[11];
    const float* v2      = (const float*)d_in[12];
    const float* g2      = (const float*)d_in[13];
    const float* k0      = (const float*)d_in[14];
    const float* k2      = (const float*)d_in[15];
    const float* r_k     = (const float*)d_in[16];
    const float* RKV_w   = (const float*)d_in[17];
    const float* O_w     = (const float*)d_in[18];
    const float* R_bias  = (const float*)d_in[19];
    const float* K_bias  = (const float*)d_in[20];
    const float* V_bias  = (const float*)d_in[21];
    const float* O_bias  = (const float*)d_in[22];
    const float* ln_r    = (const float*)d_in[23];
    const float* ln_k    = (const float*)d_in[24];
    const float* ln1     = (const float*)d_in[25];
    float* out = (float*)d_out;

    char* ws = (char*)d_ws;
    size_t off = 0;
    auto alloc = [&](size_t bytes) -> char* {
        char* p = ws + off;
        off = (off + bytes + 255) & ~(size_t)255;
        return p;
    };
    // ---- persistent region (~101 MB) ----
    char*  SCb = alloc((size_t)64 * T_ * 896);                        // compose -> pass1
    __hip_bfloat16* Ub = (__hip_bfloat16*)SCb;                        // aliases SCb (pass3 -> final gemm)
    __hip_bfloat16* VBb = (__hip_bfloat16*)alloc((size_t)MTOK * HN_ * 2); // compose -> pass3
    __hip_bfloat16* Gb  = (__hip_bfloat16*)alloc((size_t)MTOK * HN_ * 2); // compose -> pass3
    float* SBf = (float*)alloc((size_t)MTOK * H_ * 4);                // compose -> pass3
    float* Of  = (float*)alloc((size_t)MTOK * HN_ * 4);               // pass1 -> pass3 (oloc)
    __hip_bfloat16* OWb = (__hip_bfloat16*)alloc((size_t)2048 * 2048 * 2); // prep -> final gemm

    // ---- overlapped region: stage A (pre-scan, ~123 MB) ----
    size_t ovl = off;
    float* SMf = (float*)alloc((size_t)MTOK * SMN * 4);               // gemm3 -> compose
    __hip_bfloat16* Xb     = (__hip_bfloat16*)alloc((size_t)MTOK * HN_ * 2);
    __hip_bfloat16* RKVb   = (__hip_bfloat16*)alloc((size_t)3072 * 2048 * 2);
    __hip_bfloat16* WT1b   = (__hip_bfloat16*)alloc((size_t)320 * 2048 * 2);
    __hip_bfloat16* Wcatb  = (__hip_bfloat16*)alloc((size_t)SMN * KCAT * 2);
    __hip_bfloat16* XWmodb = (__hip_bfloat16*)alloc((size_t)MTOK * KCAT * 2);
    float* RKVf  = (float*)alloc((size_t)MTOK * 3072 * 4);
    float* XWp   = (float*)alloc((size_t)4 * MTOK * KCAT * 4);        // split-K partials
    // ---- overlapped region: stage B (scan, ~50 MB) — reuses stage A space ----
    off = ovl;
    float* Qf  = (float*)alloc((size_t)NCHUNK * CH * 64 * 4);         // pass1 -> pass3
    float* Pff = (float*)alloc((size_t)NCHUNK * 4096 * 4);            // pass1 -> pass2
    float* Sff = (float*)alloc((size_t)NCHUNK * 4096 * 4);            // pass1 -> pass3

    // merged weight prep (4 elems/thread)
    {
        long total4 = ((long)PREP_N1 + PREP_N2 + PREP_N3 + PREP_N4) / 4;
        prep_kernel<<<(int)((total4 + 255) / 256), 256, 0, stream>>>(
            RKV_w, O_w, wavgk1, w2, a2, v2, g2, k2, RKVb, OWb, WT1b, Wcatb);
    }

    // x = rmsnorm(x_in, ln1) -> bf16
    rmsnorm_kernel<<<MTOK, 256, 0, stream>>>(x_in, ln1, Xb);

    // big GEMMs (global_load_lds 128-tile, XCD-swizzled 1D grid)
    gemm_bt128<<<(3072 / 128) * (MTOK / 128), 256, 0, stream>>>(Xb, RKVb, RKVf, MTOK, 3072, 2048, nullptr, nullptr);
    gemm_xw_sk<<<dim3(KCAT / 64, MTOK / 64, 4), 256, 0, stream>>>(Xb, WT1b, XWp, MTOK, KCAT, 2048);
    xw_reduce<<<(MTOK * KCAT + 255) / 256, 256, 0, stream>>>(XWp, XWmodb);
    gemm_bt128_seg<<<(SMN / 128) * (MTOK / 128), 256, 0, stream>>>(XWmodb, Wcatb, SMf);

    // compose scan records (+ G gate, VB, SB)
    compose_kernel<<<MTOK, 256, 0, stream>>>(RKVf, SMf, v_first, k_first, calc_cos, calc_sin,
                                             R_bias, K_bias, V_bias, w0, a0, v0, k0,
                                             ln_r, ln_k, r_k, SCb, VBb, SBf, Gb);

    // chunked RWKV scan: pass1 -> pass2 (chunk-sequential) -> pass3+post
    scan_pass1<<<NCHUNK, 256, 0, stream>>>(SCb, Qf, Of, Pff, Sff);
    scan_pass2<<<B_ * H_ * 4, 256, 0, stream>>>(Pff, Sff, state);
    pass3_post<<<NCHUNK, 64, 0, stream>>>(Qf, Sff, Of, SBf, VBb, Gb, Ub);

    // output GEMM (adds x_in and O_bias in epilogue)
    gemm_bt128<<<(HN_ / 128) * (MTOK / 128), 256, 0, stream>>>(Ub, OWb, out, MTOK, HN_, 2048, O_bias, x_in);
}

// Round 15
// 389.736 us; speedup vs baseline: 1.0795x; 1.0069x over previous
//
#include <hip/hip_runtime.h>
#include <hip/hip_bf16.h>
#include <stdint.h>

// Problem constants
#define B_ 2
#define T_ 1024
#define H_ 32
#define N_ 64
#define HN_ 2048
#define KVH_ 8
#define KVD_ 512
#define MTOK 2048        // B*T
#define SMN 7168         // concat small-gemm output width
#define KCAT 320
#define CH 64            // scan chunk length
#define NCH 16           // T/CH
#define NCHUNK 1024      // B*H*NCH

typedef __bf16 bf16x8 __attribute__((ext_vector_type(8)));
typedef float f32x4 __attribute__((ext_vector_type(4)));
typedef float f32x2 __attribute__((ext_vector_type(2)));

typedef __attribute__((address_space(1))) uint32_t gu32;
typedef __attribute__((address_space(3))) uint32_t lu32;
__device__ __forceinline__ void gload16(const void* g, void* l) {
    __builtin_amdgcn_global_load_lds((gu32*)g, (lu32*)l, 16, 0, 0);
}

__device__ __forceinline__ float sigmf(float x) { return 1.f / (1.f + expf(-x)); }

// ---------------- merged prep kernel (4 elems/thread, 8B bf16 stores) ----------------
#define PREP_N1 (3072 * 2048)
#define PREP_N2 (2048 * 2048)
#define PREP_N3 (320 * 2048)
#define PREP_N4 (SMN * KCAT)
__global__ void prep_kernel(const float* __restrict__ RKV_w, const float* __restrict__ O_w,
                            const float* __restrict__ wavgk1,
                            const float* __restrict__ w2, const float* __restrict__ a2,
                            const float* __restrict__ v2, const float* __restrict__ g2,
                            const float* __restrict__ k2,
                            __hip_bfloat16* __restrict__ RKVb, __hip_bfloat16* __restrict__ OWb,
                            __hip_bfloat16* __restrict__ WT1b, __hip_bfloat16* __restrict__ Wcatb) {
    long i = ((long)blockIdx.x * 256 + threadIdx.x) * 4;
    __align__(8) __hip_bfloat16 t[4];
    if (i < PREP_N1) {
        float4 v = *(const float4*)&RKV_w[i];
        t[0] = __float2bfloat16(v.x); t[1] = __float2bfloat16(v.y);
        t[2] = __float2bfloat16(v.z); t[3] = __float2bfloat16(v.w);
        *(uint2*)&RKVb[i] = *(const uint2*)t;
        return;
    }
    i -= PREP_N1;
    if (i < PREP_N2) {
        float4 v = *(const float4*)&O_w[i];
        t[0] = __float2bfloat16(v.x); t[1] = __float2bfloat16(v.y);
        t[2] = __float2bfloat16(v.z); t[3] = __float2bfloat16(v.w);
        *(uint2*)&OWb[i] = *(const uint2*)t;
        return;
    }
    i -= PREP_N2;
    if (i < PREP_N3) {
        int c = (int)(i / 2048), r = (int)(i % 2048);   // 4 consecutive i share c (2048%4==0)
        #pragma unroll
        for (int j = 0; j < 4; ++j)
            t[j] = __float2bfloat16(wavgk1[(size_t)(r + j) * KCAT + c]);
        *(uint2*)&WT1b[i] = *(const uint2*)t;
        return;
    }
    i -= PREP_N3;
    if (i >= PREP_N4) return;
    int j = (int)(i / KCAT), k = (int)(i % KCAT);       // 4 consecutive share j (320%4==0)
    #pragma unroll
    for (int e = 0; e < 4; ++e) {
        int kk = k + e;
        float v = 0.f;
        if (j < 2048)      { if (kk < 64)              v = w2[(size_t)kk * 2048 + j]; }
        else if (j < 4096) { if (kk >= 64 && kk < 128)  v = a2[(size_t)(kk - 64) * 2048 + (j - 2048)]; }
        else if (j < 4608) { if (kk >= 128 && kk < 160) v = v2[(size_t)(kk - 128) * 512 + (j - 4096)]; }
        else if (j < 6656) { if (kk >= 160 && kk < 288) v = g2[(size_t)(kk - 160) * 2048 + (j - 4608)]; }
        else               { if (kk >= 288)             v = k2[(size_t)(kk - 288) * 512 + (j - 6656)]; }
        t[e] = __float2bfloat16(v);
    }
    *(uint2*)&Wcatb[i] = *(const uint2*)t;
}

// ---------------- RMSNorm over HN per token -> bf16 ----------------
__global__ __launch_bounds__(256) void rmsnorm_kernel(const float* __restrict__ x,
                                                      const float* __restrict__ ln1,
                                                      __hip_bfloat16* __restrict__ out) {
    const int bt = blockIdx.x, tid = threadIdx.x;
    const float* row = x + (size_t)bt * HN_;
    float4 v0 = *(const float4*)(row + tid * 8);
    float4 v1 = *(const float4*)(row + tid * 8 + 4);
    float s = v0.x*v0.x + v0.y*v0.y + v0.z*v0.z + v0.w*v0.w
            + v1.x*v1.x + v1.y*v1.y + v1.z*v1.z + v1.w*v1.w;
    for (int m = 1; m < 64; m <<= 1) s += __shfl_xor(s, m);
    __shared__ float red[4];
    if ((tid & 63) == 0) red[tid >> 6] = s;
    __syncthreads();
    s = red[0] + red[1] + red[2] + red[3];
    float scale = rsqrtf(s * (1.f / HN_) + 1e-6f);
    float vals[8] = {v0.x, v0.y, v0.z, v0.w, v1.x, v1.y, v1.z, v1.w};
    __align__(16) __hip_bfloat16 tmp[8];
    #pragma unroll
    for (int j = 0; j < 8; ++j)
        tmp[j] = __float2bfloat16(vals[j] * scale * ln1[tid * 8 + j]);
    *(uint4*)&out[(size_t)bt * HN_ + tid * 8] = *(const uint4*)tmp;
}

// ---------------- split-K 64-tile GEMM for XW (N=320): partial f32 out ----------------
__global__ __launch_bounds__(256) void gemm_xw_sk(const __hip_bfloat16* __restrict__ A,
                                                  const __hip_bfloat16* __restrict__ B,
                                                  float* __restrict__ Cp, int M, int N, int K) {
    __shared__ __align__(16) __hip_bfloat16 As[64][40];
    __shared__ __align__(16) __hip_bfloat16 Bs[64][40];
    const int tid = threadIdx.x;
    const int wave = tid >> 6, lane = tid & 63;
    const int wr = (wave >> 1) * 32, wc = (wave & 1) * 32;
    const int brow = blockIdx.y << 6, bcol = blockIdx.x << 6;
    const int z = blockIdx.z;
    const int kbeg = z * (K >> 2), kend = kbeg + (K >> 2);
    const int lrow = tid >> 2, lcol = (tid & 3) << 3;
    const int fr = lane & 15, ko = (lane >> 4) << 3;
    f32x4 acc[2][2] = {};
    for (int k0 = kbeg; k0 < kend; k0 += 32) {
        uint4 av = *(const uint4*)(A + (size_t)(brow + lrow) * K + k0 + lcol);
        uint4 bv = *(const uint4*)(B + (size_t)(bcol + lrow) * K + k0 + lcol);
        *(uint4*)(&As[lrow][lcol]) = av;
        *(uint4*)(&Bs[lrow][lcol]) = bv;
        __syncthreads();
        bf16x8 af0 = *(const bf16x8*)(&As[wr + fr][ko]);
        bf16x8 af1 = *(const bf16x8*)(&As[wr + 16 + fr][ko]);
        bf16x8 bf0 = *(const bf16x8*)(&Bs[wc + fr][ko]);
        bf16x8 bf1 = *(const bf16x8*)(&Bs[wc + 16 + fr][ko]);
        acc[0][0] = __builtin_amdgcn_mfma_f32_16x16x32_bf16(af0, bf0, acc[0][0], 0, 0, 0);
        acc[0][1] = __builtin_amdgcn_mfma_f32_16x16x32_bf16(af0, bf1, acc[0][1], 0, 0, 0);
        acc[1][0] = __builtin_amdgcn_mfma_f32_16x16x32_bf16(af1, bf0, acc[1][0], 0, 0, 0);
        acc[1][1] = __builtin_amdgcn_mfma_f32_16x16x32_bf16(af1, bf1, acc[1][1], 0, 0, 0);
        __syncthreads();
    }
    const int cr = (lane >> 4) << 2, cc = lane & 15;
    float* Cz = Cp + (size_t)z * M * N;
    #pragma unroll
    for (int i = 0; i < 2; ++i)
        #pragma unroll
        for (int j = 0; j < 2; ++j)
            #pragma unroll
            for (int r = 0; r < 4; ++r) {
                int row = brow + wr + i * 16 + cr + r;
                int col = bcol + wc + j * 16 + cc;
                Cz[(size_t)row * N + col] = acc[i][j][r];
            }
}

// ---------------- reduce split-K partials + xw activation -> bf16 ----------------
__global__ void xw_reduce(const float* __restrict__ Cp, __hip_bfloat16* __restrict__ out) {
    long i = (long)blockIdx.x * 256 + threadIdx.x;
    if (i >= (long)MTOK * KCAT) return;
    const long MN = (long)MTOK * KCAT;
    float v = Cp[i] + Cp[i + MN] + Cp[i + 2 * MN] + Cp[i + 3 * MN];
    int c = (int)(i % KCAT);
    if (c < 64) v = tanhf(v);
    else if (c >= 160 && c < 288) v = sigmf(v);
    out[i] = __float2bfloat16(v);
}

// ---------------- 128-tile MFMA GEMM, global_load_lds staging + XCD swizzle ----------------
__global__ __launch_bounds__(256) void gemm_bt128(const __hip_bfloat16* __restrict__ A,
                                                  const __hip_bfloat16* __restrict__ B,
                                                  float* __restrict__ C, int M, int N, int K,
                                                  const float* __restrict__ bias,
                                                  const float* __restrict__ addend) {
    __shared__ __align__(16) __hip_bfloat16 As[128][32];
    __shared__ __align__(16) __hip_bfloat16 Bs[128][32];
    const int nwg = gridDim.x;
    int wg = blockIdx.x;
    wg = (wg & 7) * (nwg >> 3) + (wg >> 3);     // XCD swizzle (bijective: nwg%8==0)
    const int nx = N >> 7;
    const int bx = wg % nx, by = wg / nx;
    const int brow = by << 7, bcol = bx << 7;
    const int tid = threadIdx.x;
    const int wave = tid >> 6, lane = tid & 63;
    const int wr = (wave >> 1) * 64, wc = (wave & 1) * 64;
    const int fr = lane & 15, ko = (lane >> 4) << 3;
    const int ar0 = wave * 32;
    const int sr = lane >> 2;
    const int sc = (lane & 3) << 3;
    f32x4 acc[4][4] = {};
    const __hip_bfloat16* gA0 = A + (size_t)(brow + ar0 + sr) * K + sc;
    const __hip_bfloat16* gA1 = A + (size_t)(brow + ar0 + 16 + sr) * K + sc;
    const __hip_bfloat16* gB0 = B + (size_t)(bcol + ar0 + sr) * K + sc;
    const __hip_bfloat16* gB1 = B + (size_t)(bcol + ar0 + 16 + sr) * K + sc;
    for (int k0 = 0; k0 < K; k0 += 32) {
        gload16(gA0 + k0, &As[ar0][0]);
        gload16(gA1 + k0, &As[ar0 + 16][0]);
        gload16(gB0 + k0, &Bs[ar0][0]);
        gload16(gB1 + k0, &Bs[ar0 + 16][0]);
        __syncthreads();
        bf16x8 af[4], bfr[4];
        #pragma unroll
        for (int i = 0; i < 4; ++i) {
            af[i]  = *(const bf16x8*)(&As[wr + i * 16 + fr][ko]);
            bfr[i] = *(const bf16x8*)(&Bs[wc + i * 16 + fr][ko]);
        }
        #pragma unroll
        for (int i = 0; i < 4; ++i)
            #pragma unroll
            for (int j = 0; j < 4; ++j)
                acc[i][j] = __builtin_amdgcn_mfma_f32_16x16x32_bf16(af[i], bfr[j], acc[i][j], 0, 0, 0);
        __syncthreads();
    }
    const int cr = (lane >> 4) << 2, cc = lane & 15;
    #pragma unroll
    for (int i = 0; i < 4; ++i)
        #pragma unroll
        for (int j = 0; j < 4; ++j) {
            const int row0 = brow + wr + i * 16 + cr;
            const int col = bcol + wc + j * 16 + cc;
            #pragma unroll
            for (int r = 0; r < 4; ++r) {
                float v = acc[i][j][r];
                if (bias) v += bias[col];
                if (addend) v += addend[(size_t)(row0 + r) * N + col];
                C[(size_t)(row0 + r) * N + col] = v;
            }
        }
}

// ---------------- segment-aware 128-tile GEMM for SMf (block-diagonal Wcat) ----------------
__global__ __launch_bounds__(256) void gemm_bt128_seg(const __hip_bfloat16* __restrict__ A,
                                                      const __hip_bfloat16* __restrict__ B,
                                                      float* __restrict__ C) {
    const int M = MTOK, N = SMN, K = KCAT;
    __shared__ __align__(16) __hip_bfloat16 As[128][32];
    __shared__ __align__(16) __hip_bfloat16 Bs[128][32];
    const int nwg = gridDim.x;
    int wg = blockIdx.x;
    wg = (wg & 7) * (nwg >> 3) + (wg >> 3);
    const int nx = N >> 7;
    const int bx = wg % nx, by = wg / nx;
    const int brow = by << 7, bcol = bx << 7;
    int kbeg, kend;
    if (bcol < 2048)      { kbeg = 0;   kend = 64;  }
    else if (bcol < 4096) { kbeg = 64;  kend = 128; }
    else if (bcol < 4608) { kbeg = 128; kend = 160; }
    else if (bcol < 6656) { kbeg = 160; kend = 288; }
    else                  { kbeg = 288; kend = 320; }
    const int tid = threadIdx.x;
    const int wave = tid >> 6, lane = tid & 63;
    const int wr = (wave >> 1) * 64, wc = (wave & 1) * 64;
    const int fr = lane & 15, ko = (lane >> 4) << 3;
    const int ar0 = wave * 32;
    const int sr = lane >> 2;
    const int sc = (lane & 3) << 3;
    f32x4 acc[4][4] = {};
    const __hip_bfloat16* gA0 = A + (size_t)(brow + ar0 + sr) * K + sc;
    const __hip_bfloat16* gA1 = A + (size_t)(brow + ar0 + 16 + sr) * K + sc;
    const __hip_bfloat16* gB0 = B + (size_t)(bcol + ar0 + sr) * K + sc;
    const __hip_bfloat16* gB1 = B + (size_t)(bcol + ar0 + 16 + sr) * K + sc;
    for (int k0 = kbeg; k0 < kend; k0 += 32) {
        gload16(gA0 + k0, &As[ar0][0]);
        gload16(gA1 + k0, &As[ar0 + 16][0]);
        gload16(gB0 + k0, &Bs[ar0][0]);
        gload16(gB1 + k0, &Bs[ar0 + 16][0]);
        __syncthreads();
        bf16x8 af[4], bfr[4];
        #pragma unroll
        for (int i = 0; i < 4; ++i) {
            af[i]  = *(const bf16x8*)(&As[wr + i * 16 + fr][ko]);
            bfr[i] = *(const bf16x8*)(&Bs[wc + i * 16 + fr][ko]);
        }
        #pragma unroll
        for (int i = 0; i < 4; ++i)
            #pragma unroll
            for (int j = 0; j < 4; ++j)
                acc[i][j] = __builtin_amdgcn_mfma_f32_16x16x32_bf16(af[i], bfr[j], acc[i][j], 0, 0, 0);
        __syncthreads();
    }
    const int cr = (lane >> 4) << 2, cc = lane & 15;
    #pragma unroll
    for (int i = 0; i < 4; ++i)
        #pragma unroll
        for (int j = 0; j < 4; ++j) {
            const int row0 = brow + wr + i * 16 + cr;
            const int col = bcol + wc + j * 16 + cc;
            #pragma unroll
            for (int r = 0; r < 4; ++r)
                C[(size_t)(row0 + r) * N + col] = acc[i][j][r];
        }
}

// ---------------- compose: per-token head math -> packed scan records + VB/G/SB ----------------
__global__ __launch_bounds__(256) void compose_kernel(
    const float* __restrict__ RKV, const float* __restrict__ SM,
    const float* __restrict__ v_first, const float* __restrict__ k_first,
    const float* __restrict__ cosd, const float* __restrict__ sind,
    const float* __restrict__ R_bias, const float* __restrict__ K_bias,
    const float* __restrict__ V_bias, const float* __restrict__ w0,
    const float* __restrict__ a0, const float* __restrict__ v0b,
    const float* __restrict__ k0b, const float* __restrict__ ln_r,
    const float* __restrict__ ln_k, const float* __restrict__ r_k,
    char* __restrict__ SC, __hip_bfloat16* __restrict__ VB, float* __restrict__ SB,
    __hip_bfloat16* __restrict__ G) {
    __shared__ __align__(16) float rbuf[HN_];
    __shared__ __align__(16) float kbuf[KVD_];
    __shared__ __align__(16) float vbuf[KVD_];
    __shared__ float knorms[KVH_];
    __shared__ float cosb[64], sinb[64];
    const int bt = blockIdx.x;
    const int b = bt >> 10, t = bt & 1023;
    const int tid = threadIdx.x;
    const float* rkvrow = RKV + (size_t)bt * 3072;
    const float* smrow = SM + (size_t)bt * SMN;

    if (tid < 64) {
        cosb[tid] = cosd[(size_t)bt * 64 + tid];
        sinb[tid] = sind[(size_t)bt * 64 + tid];
    }

    const int h = tid >> 3;
    const int off = (tid & 7) << 3;
    const int n0 = tid << 3;
    float rraw[8];
    {
        float4 x0 = *(const float4*)(rkvrow + n0);
        float4 x1 = *(const float4*)(rkvrow + n0 + 4);
        float4 b0 = *(const float4*)(R_bias + n0);
        float4 b1 = *(const float4*)(R_bias + n0 + 4);
        rraw[0] = x0.x + b0.x; rraw[1] = x0.y + b0.y; rraw[2] = x0.z + b0.z; rraw[3] = x0.w + b0.w;
        rraw[4] = x1.x + b1.x; rraw[5] = x1.y + b1.y; rraw[6] = x1.z + b1.z; rraw[7] = x1.w + b1.w;
    }
    float rss = 0.f;
    #pragma unroll
    for (int j = 0; j < 8; ++j) { rss += rraw[j] * rraw[j]; rbuf[n0 + j] = rraw[j]; }
    rss += __shfl_xor(rss, 1); rss += __shfl_xor(rss, 2); rss += __shfl_xor(rss, 4);
    float rscale = rsqrtf(rss * (1.f / 64.f) + 1e-6f);

    const int kvh = tid >> 5;
    const int ko2 = (tid & 31) << 1;
    const int kidx = kvh * 64 + ko2;
    float kraw0 = rkvrow[2048 + kidx] + K_bias[kidx];
    float kraw1 = rkvrow[2048 + kidx + 1] + K_bias[kidx + 1];
    float kss = kraw0 * kraw0 + kraw1 * kraw1;
    kss += __shfl_xor(kss, 1); kss += __shfl_xor(kss, 2); kss += __shfl_xor(kss, 4);
    kss += __shfl_xor(kss, 8); kss += __shfl_xor(kss, 16);
    float kscale = rsqrtf(kss * (1.f / 64.f) + 1e-6f);
    kbuf[kidx] = kraw0; kbuf[kidx + 1] = kraw1;

    {
        float va = rkvrow[2560 + kidx] + V_bias[kidx];
        float vb2 = rkvrow[2560 + kidx + 1] + V_bias[kidx + 1];
        float gv0 = sigmf(smrow[4096 + kidx] + v0b[kidx]);
        float gv1 = sigmf(smrow[4096 + kidx + 1] + v0b[kidx + 1]);
        vbuf[kidx] = va + (v_first[(size_t)bt * 512 + kidx] - va) * gv0;
        vbuf[kidx + 1] = vb2 + (v_first[(size_t)bt * 512 + kidx + 1] - vb2) * gv1;
    }
    __syncthreads();

    float rf[8];
    #pragma unroll
    for (int j = 0; j < 8; ++j) {
        int nn = off + j;
        int nn2 = (nn + 32) & 63;
        float val = rbuf[h * 64 + nn] * rscale * ln_r[nn];
        float oth = rbuf[h * 64 + nn2] * rscale * ln_r[nn2];
        float rot = (nn < 32) ? -oth : oth;
        rf[j] = val * cosb[nn] + rot * sinb[nn];
    }
    float kfv[2];
    #pragma unroll
    for (int j = 0; j < 2; ++j) {
        int nn = ko2 + j;
        int nn2 = (nn + 32) & 63;
        float val = kbuf[kvh * 64 + nn] * kscale * ln_k[nn];
        float oth = kbuf[kvh * 64 + nn2] * kscale * ln_k[nn2];
        float rot = (nn < 32) ? -oth : oth;
        float kr = val * cosb[nn] + rot * sinb[nn];
        float gk = sigmf(smrow[6656 + kvh * 64 + nn] + k0b[kvh * 64 + nn]);
        kfv[j] = kr + (k_first[(size_t)bt * 512 + kvh * 64 + nn] - kr) * gk;
    }
    __syncthreads();
    kbuf[kidx] = kfv[0]; kbuf[kidx + 1] = kfv[1];
    float kn = kfv[0] * kfv[0] + kfv[1] * kfv[1];
    kn += __shfl_xor(kn, 1); kn += __shfl_xor(kn, 2); kn += __shfl_xor(kn, 4);
    kn += __shfl_xor(kn, 8); kn += __shfl_xor(kn, 16);
    if ((tid & 31) == 0) knorms[kvh] = fmaxf(sqrtf(kn), 1e-12f);
    __syncthreads();

    const float knv = knorms[h >> 2];
    char* scb = SC + ((size_t)(b * H_ + h) * T_ + t) * 896;
    __hip_bfloat16* us = (__hip_bfloat16*)scb;
    float* df = (float*)(scb + 640);
    float4 w1a = *(const float4*)(smrow + n0);
    float4 w1b = *(const float4*)(smrow + n0 + 4);
    float4 ara = *(const float4*)(smrow + 2048 + n0);
    float4 arb = *(const float4*)(smrow + 2048 + n0 + 4);
    float4 ga  = *(const float4*)(smrow + 4608 + n0);
    float4 gb  = *(const float4*)(smrow + 4608 + n0 + 4);
    float w1arr[8] = {w1a.x, w1a.y, w1a.z, w1a.w, w1b.x, w1b.y, w1b.z, w1b.w};
    float aarr[8] = {ara.x, ara.y, ara.z, ara.w, arb.x, arb.y, arb.z, arb.w};
    float garr[8] = {ga.x, ga.y, ga.z, ga.w, gb.x, gb.y, gb.z, gb.w};
    __align__(16) __hip_bfloat16 t_r[8], t_k[8], t_a[8], t_b[8], t_v[8], t_vb[8], t_g[8];
    __align__(16) float t_d[8];
    float bsum = 0.f;
    #pragma unroll
    for (int j = 0; j < 8; ++j) {
        int nn = off + j, n = n0 + j;
        float w1 = w1arr[j] + w0[n];
        float w2v = -log1pf(expf(-w1)) - 0.5f;
        float av = sigmf(aarr[j] + a0[n]);
        float dec = expf(-expf(w2v));
        float kb = kbuf[(h >> 2) * 64 + nn];
        float vbv = vbuf[(h >> 2) * 64 + nn];
        float kkv = kb / knv;
        float ksc = kb * (1.f - w2v + av);
        t_r[j] = __float2bfloat16(rf[j]);
        t_k[j] = __float2bfloat16(ksc);
        t_a[j] = __float2bfloat16(-kkv);
        t_b[j] = __float2bfloat16(kkv * av);
        t_v[j] = __float2bfloat16(vbv);
        t_d[j] = dec;
        t_vb[j] = __float2bfloat16(vbv);
        t_g[j] = __float2bfloat16(garr[j]);
        bsum += rf[j] * ksc * r_k[h * 64 + nn];
    }
    *(uint4*)&us[off]        = *(const uint4*)t_r;
    *(uint4*)&us[64 + off]   = *(const uint4*)t_k;
    *(uint4*)&us[128 + off]  = *(const uint4*)t_a;
    *(uint4*)&us[192 + off]  = *(const uint4*)t_b;
    *(uint4*)&us[256 + off]  = *(const uint4*)t_v;
    *(float4*)&df[off]       = *(const float4*)&t_d[0];
    *(float4*)&df[off + 4]   = *(const float4*)&t_d[4];
    *(uint4*)&VB[(size_t)bt * HN_ + n0] = *(const uint4*)t_vb;
    *(uint4*)&G[(size_t)bt * HN_ + n0]  = *(const uint4*)t_g;
    bsum += __shfl_xor(bsum, 1); bsum += __shfl_xor(bsum, 2); bsum += __shfl_xor(bsum, 4);
    if ((tid & 7) == 0) SB[bt * H_ + h] = bsum;
}

// ---------------- chunked scan pass 1 (4-wave unified): wave w owns rows [16w,16w+16) of BOTH P,S ----------------
__global__ __launch_bounds__(256) void scan_pass1(
    const char* __restrict__ SC, float* __restrict__ Q, float* __restrict__ O,
    float* __restrict__ Pf, float* __restrict__ Sf) {
    const int chunk = blockIdx.x;
    const int bh = chunk >> 4, c = chunk & 15;
    const int b = bh >> 5, h = bh & 31;
    const int tid = threadIdx.x;
    const int wid = tid >> 6, lane = tid & 63;
    const int cq = lane >> 4;            // col quarter
    const int cb = cq << 4;              // col base
    const int row = (wid << 4) + (lane & 15);
    const char* base = SC + ((size_t)bh * T_ + (size_t)c * CH) * 896;
    __shared__ __align__(16) float ld[2][6][64];  // 0=a 1=b 2=d 3=k 4=r 5=v

    f32x4 P4[4], S4[4];
    #pragma unroll
    for (int j = 0; j < 4; ++j)
        #pragma unroll
        for (int e = 0; e < 4; ++e) {
            P4[j][e] = (cb + 4 * j + e == row) ? 1.f : 0.f;
            S4[j][e] = 0.f;
        }

    float p0 = 0.f, p1 = 0.f;
    auto LOADT = [&](int t) {
        const __hip_bfloat16* us = (const __hip_bfloat16*)(base + (size_t)t * 896);
        if (wid == 0)      { p0 = __bfloat162float(us[128 + lane]); p1 = __bfloat162float(us[lane]); }       // a, r
        else if (wid == 1) { p0 = __bfloat162float(us[192 + lane]); p1 = __bfloat162float(us[256 + lane]); } // b, v
        else if (wid == 2) { p0 = *(const float*)(base + (size_t)t * 896 + 640 + 4 * lane); }                // d
        else               { p0 = __bfloat162float(us[64 + lane]); }                                         // k
    };
    LOADT(0);
    float* qrow = Q + (size_t)chunk * CH * 64 + row;
    float* orow = O + ((size_t)b * T_ + (size_t)c * CH) * HN_ + h * 64 + row;
    for (int t = 0; t < CH; ++t) {
        const int buf = t & 1;
        if (wid == 0)      { ld[buf][0][lane] = p0; ld[buf][4][lane] = p1; }
        else if (wid == 1) { ld[buf][1][lane] = p0; ld[buf][5][lane] = p1; }
        else if (wid == 2) { ld[buf][2][lane] = p0; }
        else               { ld[buf][3][lane] = p0; }
        __syncthreads();
        if (t + 1 < CH) LOADT(t + 1);
        f32x4 a4[4];
        #pragma unroll
        for (int j = 0; j < 4; ++j) a4[j] = *(const f32x4*)&ld[buf][0][cb + 4 * j];
        f32x4 dpv = {0,0,0,0}, dsv = {0,0,0,0};
        #pragma unroll
        for (int j = 0; j < 4; ++j) { dpv += P4[j] * a4[j]; dsv += S4[j] * a4[j]; }
        float dp = dpv[0] + dpv[1] + dpv[2] + dpv[3];
        float dsd = dsv[0] + dsv[1] + dsv[2] + dsv[3];
        dp += __shfl_xor(dp, 16);  dp += __shfl_xor(dp, 32);
        dsd += __shfl_xor(dsd, 16); dsd += __shfl_xor(dsd, 32);
        const float vt = ld[buf][5][row];
        const f32x4 cPv = {dp, dp, dp, dp}, sav = {dsd, dsd, dsd, dsd}, vtv = {vt, vt, vt, vt};
        f32x4 qp = {0,0,0,0}, op = {0,0,0,0};
        #pragma unroll
        for (int j = 0; j < 4; ++j) {
            f32x4 d4 = *(const f32x4*)&ld[buf][2][cb + 4 * j];
            f32x4 b4 = *(const f32x4*)&ld[buf][1][cb + 4 * j];
            f32x4 k4 = *(const f32x4*)&ld[buf][3][cb + 4 * j];
            f32x4 r4 = *(const f32x4*)&ld[buf][4][cb + 4 * j];
            f32x4 Pn = P4[j] * d4 + cPv * b4;
            f32x4 Sn = S4[j] * d4 + sav * b4 + vtv * k4;
            P4[j] = Pn; S4[j] = Sn;
            qp += Pn * r4; op += Sn * r4;
        }
        float qs = qp[0] + qp[1] + qp[2] + qp[3];
        float os = op[0] + op[1] + op[2] + op[3];
        qs += __shfl_xor(qs, 16); qs += __shfl_xor(qs, 32);
        os += __shfl_xor(os, 16); os += __shfl_xor(os, 32);
        if (cq == 0) {
            qrow[(size_t)t * 64] = qs;
            orow[(size_t)t * HN_] = os;   // oloc, unscaled
        }
    }
    float* pf = Pf + (size_t)chunk * 4096 + (size_t)row * 64 + cb;
    float* sf = Sf + (size_t)chunk * 4096 + (size_t)row * 64 + cb;
    #pragma unroll
    for (int j = 0; j < 4; ++j) {
        *(f32x4*)(pf + 4 * j) = P4[j];
        *(f32x4*)(sf + 4 * j) = S4[j];
    }
}

// ---------------- pass 2: propagate chunk-initial states (Sf -> Sinit in place) ----------------
// 8 blocks per bh (row-split: 8 S-rows each); thread owns one f32x2 of S.
__global__ __launch_bounds__(256) void scan_pass2(
    const float* __restrict__ Pf, float* __restrict__ Sf, const float* __restrict__ state) {
    const int blk = blockIdx.x;
    const int bh = blk >> 3, rb = blk & 7;
    const int tid = threadIdx.x;
    const int lv = tid >> 5, c0 = (tid & 31) << 1;
    __shared__ __align__(16) float S[8][66];
    __shared__ __align__(16) float P[64][64];

    *(f32x2*)&S[lv][c0] = *(const f32x2*)&state[(size_t)bh * 4096 + 512 * rb + tid * 2];
    const size_t pbase = (size_t)(bh * NCH) * 4096;
    {
        f32x4 p0[4];
        #pragma unroll
        for (int j = 0; j < 4; ++j) p0[j] = *(const f32x4*)&Pf[pbase + tid * 16 + 4 * j];
        #pragma unroll
        for (int j = 0; j < 4; ++j) *(f32x4*)(&P[0][0] + tid * 16 + 4 * j) = p0[j];
    }
    __syncthreads();

    for (int c = 0; c < NCH; ++c) {
        const size_t ck = (size_t)(bh * NCH + c) * 4096;
        f32x4 pp[4];
        if (c + 1 < NCH) {
            #pragma unroll
            for (int j = 0; j < 4; ++j) pp[j] = *(const f32x4*)&Pf[ck + 4096 + tid * 16 + 4 * j];
        }
        f32x2 acc = *(const f32x2*)&Sf[ck + 512 * rb + tid * 2];   // S_loc(c)
        f32x2 cur = *(const f32x2*)&S[lv][c0];                     // Sinit(c)
        #pragma unroll 4
        for (int k4 = 0; k4 < 64; k4 += 4) {
            f32x4 sk4 = *(const f32x4*)&S[lv][k4];
            #pragma unroll
            for (int kk = 0; kk < 4; ++kk) {
                f32x2 pr = *(const f32x2*)&P[k4 + kk][c0];
                f32x2 sv = {sk4[kk], sk4[kk]};
                acc += sv * pr;
            }
        }
        __syncthreads();
        *(f32x2*)&S[lv][c0] = acc;
        if (c + 1 < NCH) {
            #pragma unroll
            for (int j = 0; j < 4; ++j) *(f32x4*)(&P[0][0] + tid * 16 + 4 * j) = pp[j];
        }
        *(f32x2*)&Sf[ck + 512 * rb + tid * 2] = cur;
        __syncthreads();
    }
}

// ---------------- pass 3 + post fused: u = ((Sinit·q + oloc)·N^-0.5 + SB·VB)·G -> bf16 ----------------
__global__ __launch_bounds__(64) void pass3_post(
    const float* __restrict__ Q, const float* __restrict__ Sinit, const float* __restrict__ OL,
    const float* __restrict__ SB, const __hip_bfloat16* __restrict__ VB,
    const __hip_bfloat16* __restrict__ G, __hip_bfloat16* __restrict__ Ub) {
    const int chunk = blockIdx.x;
    const int bh = chunk >> 4, c = chunk & 15;
    const int b = bh >> 5, h = bh & 31;
    const int t = threadIdx.x;
    __shared__ __align__(16) float S[64][64];
    #pragma unroll
    for (int j = 0; j < 16; ++j)
        *(f32x4*)&S[t][4 * j] = *(const f32x4*)&Sinit[(size_t)chunk * 4096 + (size_t)t * 64 + 4 * j];
    __syncthreads();
    float q[64];
    #pragma unroll
    for (int j = 0; j < 16; ++j)
        *(f32x4*)&q[4 * j] = *(const f32x4*)&Q[((size_t)chunk * CH + t) * 64 + 4 * j];
    const size_t bt = (size_t)b * T_ + (size_t)c * CH + t;
    const float sb = SB[bt * H_ + h];
    const float* olrow = OL + bt * HN_ + h * 64;
    const __hip_bfloat16* vbrow = VB + bt * HN_ + h * 64;
    const __hip_bfloat16* grow = G + bt * HN_ + h * 64;
    __hip_bfloat16* urow = Ub + bt * HN_ + h * 64;
    #pragma unroll 4
    for (int v = 0; v < 64; ++v) {
        f32x4 a = {0, 0, 0, 0};
        #pragma unroll
        for (int j = 0; j < 16; ++j)
            a += *(const f32x4*)&S[v][4 * j] * *(const f32x4*)&q[4 * j];
        float o = (a[0] + a[1] + a[2] + a[3] + olrow[v]) * 0.125f;
        float u = (o + sb * __bfloat162float(vbrow[v])) * __bfloat162float(grow[v]);
        urow[v] = __float2bfloat16(u);
    }
}

extern "C" void kernel_launch(void* const* d_in, const int* in_sizes, int n_in,
                              void* d_out, int out_size, void* d_ws, size_t ws_size,
                              hipStream_t stream) {
    (void)in_sizes; (void)n_in; (void)out_size; (void)ws_size;
    const float* x_in    = (const float*)d_in[0];
    const float* v_first = (const float*)d_in[1];
    const float* k_first = (const float*)d_in[2];
    const float* state   = (const float*)d_in[3];
    const float* calc_cos= (const float*)d_in[4];
    const float* calc_sin= (const float*)d_in[5];
    const float* wavgk1  = (const float*)d_in[6];
    const float* w0      = (const float*)d_in[7];
    const float* w2      = (const float*)d_in[8];
    const float* a0      = (const float*)d_in[9];
    const float* a2      = (const float*)d_in[10];
    const float* v0      = (const float*)d_in[11];
    const float* v2      = (const float*)d_in[12];
    const float* g2      = (const float*)d_in[13];
    const float* k0      = (const float*)d_in[14];
    const float* k2      = (const float*)d_in[15];
    const float* r_k     = (const float*)d_in[16];
    const float* RKV_w   = (const float*)d_in[17];
    const float* O_w     = (const float*)d_in[18];
    const float* R_bias  = (const float*)d_in[19];
    const float* K_bias  = (const float*)d_in[20];
    const float* V_bias  = (const float*)d_in[21];
    const float* O_bias  = (const float*)d_in[22];
    const float* ln_r    = (const float*)d_in[23];
    const float* ln_k    = (const float*)d_in[24];
    const float* ln1     = (const float*)d_in[25];
    float* out = (float*)d_out;

    char* ws = (char*)d_ws;
    size_t off = 0;
    auto alloc = [&](size_t bytes) -> char* {
        char* p = ws + off;
        off = (off + bytes + 255) & ~(size_t)255;
        return p;
    };
    // ---- persistent region (~101 MB) ----
    char*  SCb = alloc((size_t)64 * T_ * 896);                        // compose -> pass1
    __hip_bfloat16* Ub = (__hip_bfloat16*)SCb;                        // aliases SCb (pass3 -> final gemm)
    __hip_bfloat16* VBb = (__hip_bfloat16*)alloc((size_t)MTOK * HN_ * 2); // compose -> pass3
    __hip_bfloat16* Gb  = (__hip_bfloat16*)alloc((size_t)MTOK * HN_ * 2); // compose -> pass3
    float* SBf = (float*)alloc((size_t)MTOK * H_ * 4);                // compose -> pass3
    float* Of  = (float*)alloc((size_t)MTOK * HN_ * 4);               // pass1 -> pass3 (oloc)
    __hip_bfloat16* OWb = (__hip_bfloat16*)alloc((size_t)2048 * 2048 * 2); // prep -> final gemm

    // ---- overlapped region: stage A (pre-scan, ~123 MB) ----
    size_t ovl = off;
    float* SMf = (float*)alloc((size_t)MTOK * SMN * 4);               // gemm3 -> compose
    __hip_bfloat16* Xb     = (__hip_bfloat16*)alloc((size_t)MTOK * HN_ * 2);
    __hip_bfloat16* RKVb   = (__hip_bfloat16*)alloc((size_t)3072 * 2048 * 2);
    __hip_bfloat16* WT1b   = (__hip_bfloat16*)alloc((size_t)320 * 2048 * 2);
    __hip_bfloat16* Wcatb  = (__hip_bfloat16*)alloc((size_t)SMN * KCAT * 2);
    __hip_bfloat16* XWmodb = (__hip_bfloat16*)alloc((size_t)MTOK * KCAT * 2);
    float* RKVf  = (float*)alloc((size_t)MTOK * 3072 * 4);
    float* XWp   = (float*)alloc((size_t)4 * MTOK * KCAT * 4);        // split-K partials
    // ---- overlapped region: stage B (scan, ~50 MB) — reuses stage A space ----
    off = ovl;
    float* Qf  = (float*)alloc((size_t)NCHUNK * CH * 64 * 4);         // pass1 -> pass3
    float* Pff = (float*)alloc((size_t)NCHUNK * 4096 * 4);            // pass1 -> pass2
    float* Sff = (float*)alloc((size_t)NCHUNK * 4096 * 4);            // pass1 -> pass3

    // merged weight prep (4 elems/thread)
    {
        long total4 = ((long)PREP_N1 + PREP_N2 + PREP_N3 + PREP_N4) / 4;
        prep_kernel<<<(int)((total4 + 255) / 256), 256, 0, stream>>>(
            RKV_w, O_w, wavgk1, w2, a2, v2, g2, k2, RKVb, OWb, WT1b, Wcatb);
    }

    // x = rmsnorm(x_in, ln1) -> bf16
    rmsnorm_kernel<<<MTOK, 256, 0, stream>>>(x_in, ln1, Xb);

    // big GEMMs (global_load_lds 128-tile, XCD-swizzled 1D grid)
    gemm_bt128<<<(3072 / 128) * (MTOK / 128), 256, 0, stream>>>(Xb, RKVb, RKVf, MTOK, 3072, 2048, nullptr, nullptr);
    gemm_xw_sk<<<dim3(KCAT / 64, MTOK / 64, 4), 256, 0, stream>>>(Xb, WT1b, XWp, MTOK, KCAT, 2048);
    xw_reduce<<<(MTOK * KCAT + 255) / 256, 256, 0, stream>>>(XWp, XWmodb);
    gemm_bt128_seg<<<(SMN / 128) * (MTOK / 128), 256, 0, stream>>>(XWmodb, Wcatb, SMf);

    // compose scan records (+ G gate, VB, SB)
    compose_kernel<<<MTOK, 256, 0, stream>>>(RKVf, SMf, v_first, k_first, calc_cos, calc_sin,
                                             R_bias, K_bias, V_bias, w0, a0, v0, k0,
                                             ln_r, ln_k, r_k, SCb, VBb, SBf, Gb);

    // chunked RWKV scan: pass1 -> pass2 (chunk-sequential, 8-way row-split) -> pass3+post
    scan_pass1<<<NCHUNK, 256, 0, stream>>>(SCb, Qf, Of, Pff, Sff);
    scan_pass2<<<B_ * H_ * 8, 256, 0, stream>>>(Pff, Sff, state);
    pass3_post<<<NCHUNK, 64, 0, stream>>>(Qf, Sff, Of, SBf, VBb, Gb, Ub);

    // output GEMM (adds x_in and O_bias in epilogue)
    gemm_bt128<<<(HN_ / 128) * (MTOK / 128), 256, 0, stream>>>(Ub, OWb, out, MTOK, HN_, 2048, O_bias, x_in);
}